// Round 10
// baseline (491.274 us; speedup 1.0000x reference)
//
#include <hip/hip_runtime.h>
#include <math.h>

#define NN 50000
#define NE 800000
#define FIN 500
#define NCLS 40
#define NB 196  // scan blocks = ceil(NN/256)

typedef short short8 __attribute__((ext_vector_type(8)));
typedef float f32x4 __attribute__((ext_vector_type(4)));

__device__ __forceinline__ unsigned short f2bf(float f) {
    unsigned u = __float_as_uint(f);
    unsigned r = (u + 0x7FFFu + ((u >> 16) & 1u)) >> 16;
    return (unsigned short)r;
}
__device__ __forceinline__ float bf2f(unsigned short h) {
    return __uint_as_float(((unsigned)h) << 16);
}

// global -> LDS direct copy, 16B per lane; LDS dest is wave-uniform base + lane*16
typedef const __attribute__((address_space(1))) void gv1;
typedef __attribute__((address_space(3))) void lv3;
__device__ __forceinline__ void gl16(const void* g, void* l) {
    __builtin_amdgcn_global_load_lds((gv1*)g, (lv3*)l, 16, 0, 0);
}

// ---- weight split+transpose into blocked, pre-swizzled layout ----
// dst layout: [yb][ck64][r (0..BN-1)][16 x 16B-chunks: hi 0-7, lo 8-15, chunk^ (r&7)]
__global__ void k_wsplit(const float* __restrict__ W, short* __restrict__ dst,
                         int Ksrc, int Ncols, int Kpad, int BN, int koff,
                         int noff, int llog) {
    int i = blockIdx.x * 256 + threadIdx.x;
    int len = 1 << llog;
    if (i >= Ncols * len) return;
    int n = i >> llog, kk = i & (len - 1);
    float v = (kk < Ksrc) ? W[(size_t)kk * Ncols + n] : 0.f;
    unsigned short hi = f2bf(v);
    float lo = v - bf2f(hi);
    int nd = noff + n, kd = koff + kk;
    int yb = nd / BN, r = nd % BN;
    int ck = kd >> 6, kin = kd & 63;
    int c16h = (kin >> 3) ^ (r & 7);
    size_t rowb = (((size_t)yb * (Kpad >> 6) + ck) * BN + r) * 128;
    dst[rowb + c16h * 8 + (kin & 7)] = (short)hi;
    dst[rowb + (8 + c16h) * 8 + (kin & 7)] = (short)f2bf(lo);
}

// ---------------- counting sort of edges by dst ----------------
__global__ void k_count(const int* __restrict__ dst, int* __restrict__ deg) {
    int e = blockIdx.x * blockDim.x + threadIdx.x;
    if (e < NE) atomicAdd(&deg[dst[e]], 1);
}

__global__ void k_scan1(const int* __restrict__ deg, int* __restrict__ offs,
                        int* __restrict__ bsum) {
    __shared__ int sm[256];
    int tid = threadIdx.x;
    int i = blockIdx.x * 256 + tid;
    int v = (i < NN) ? deg[i] : 0;
    sm[tid] = v;
    __syncthreads();
    for (int off = 1; off < 256; off <<= 1) {
        int t = (tid >= off) ? sm[tid - off] : 0;
        __syncthreads();
        sm[tid] += t;
        __syncthreads();
    }
    if (i < NN) offs[i] = sm[tid] - v;
    if (tid == 255) bsum[blockIdx.x] = sm[255];
}

__global__ void k_scan2(const int* __restrict__ bsum, int* __restrict__ bpre,
                        int* __restrict__ offs) {
    __shared__ int sm[256];
    int tid = threadIdx.x;
    int v = (tid < NB) ? bsum[tid] : 0;
    sm[tid] = v;
    __syncthreads();
    for (int off = 1; off < 256; off <<= 1) {
        int t = (tid >= off) ? sm[tid - off] : 0;
        __syncthreads();
        sm[tid] += t;
        __syncthreads();
    }
    if (tid < NB) bpre[tid] = sm[tid] - v;
    if (tid == 255) offs[NN] = sm[255];
}

__global__ void k_scan3(int* __restrict__ offs, const int* __restrict__ bpre,
                        int* __restrict__ cursor) {
    int i = blockIdx.x * 256 + threadIdx.x;
    if (i < NN) {
        int v = offs[i] + bpre[blockIdx.x];
        offs[i] = v;
        cursor[i] = v;
    }
}

__global__ void k_scatter(const int* __restrict__ src, const int* __restrict__ dst,
                          int* __restrict__ cursor, int* __restrict__ ssrc) {
    int e = blockIdx.x * blockDim.x + threadIdx.x;
    if (e < NE) {
        int p = atomicAdd(&cursor[dst[e]], 1);
        ssrc[p] = src[e];
    }
}

// ---- mean aggregation from bf16 table [NN][128] -> bf16 mean plane [NN][128] ----
// one wave per node; 16-lane subwave per edge (16B/lane); 4 edges/subwave in flight
__global__ __launch_bounds__(256) void k_aggb(
    const short* __restrict__ hb, const int* __restrict__ offs,
    const int* __restrict__ ssrc, short* __restrict__ mH) {
    int wid = (blockIdx.x * 256 + threadIdx.x) >> 6;
    int lane = threadIdx.x & 63;
    if (wid >= NN) return;
    int sub = lane >> 4, l16 = lane & 15;
    int beg = offs[wid], end = offs[wid + 1];
    f32x4 a0 = {0.f, 0.f, 0.f, 0.f}, a1 = {0.f, 0.f, 0.f, 0.f};
    int i = beg + sub;
    for (; i + 12 < end; i += 16) {
        int s0 = ssrc[i];
        int s1 = ssrc[i + 4];
        int s2 = ssrc[i + 8];
        int s3 = ssrc[i + 12];
        short8 v0 = *(const short8*)(hb + (size_t)s0 * 128 + l16 * 8);
        short8 v1 = *(const short8*)(hb + (size_t)s1 * 128 + l16 * 8);
        short8 v2 = *(const short8*)(hb + (size_t)s2 * 128 + l16 * 8);
        short8 v3 = *(const short8*)(hb + (size_t)s3 * 128 + l16 * 8);
#pragma unroll
        for (int j = 0; j < 4; ++j) {
            a0[j] += (bf2f((unsigned short)v0[j]) + bf2f((unsigned short)v1[j])) +
                     (bf2f((unsigned short)v2[j]) + bf2f((unsigned short)v3[j]));
            a1[j] += (bf2f((unsigned short)v0[j + 4]) + bf2f((unsigned short)v1[j + 4])) +
                     (bf2f((unsigned short)v2[j + 4]) + bf2f((unsigned short)v3[j + 4]));
        }
    }
    for (; i < end; i += 4) {
        int s0 = ssrc[i];
        short8 v0 = *(const short8*)(hb + (size_t)s0 * 128 + l16 * 8);
#pragma unroll
        for (int j = 0; j < 4; ++j) {
            a0[j] += bf2f((unsigned short)v0[j]);
            a1[j] += bf2f((unsigned short)v0[j + 4]);
        }
    }
#pragma unroll
    for (int j = 0; j < 4; ++j) {
        a0[j] += __shfl_xor(a0[j], 16);
        a0[j] += __shfl_xor(a0[j], 32);
        a1[j] += __shfl_xor(a1[j], 16);
        a1[j] += __shfl_xor(a1[j], 32);
    }
    if (sub == 0) {
        float inv = 1.f / fmaxf((float)(end - beg), 1.f);
        a0 *= inv; a1 *= inv;
        short8 hv;
#pragma unroll
        for (int j = 0; j < 4; ++j) {
            hv[j] = (short)f2bf(a0[j]);
            hv[j + 4] = (short)f2bf(a1[j]);
        }
        *(short8*)(mH + (size_t)wid * 128 + l16 * 8) = hv;
    }
}

// ---------------- MFMA GEMM: counted-vmcnt pipeline, optional split-K (blockIdx.z) ----------------
// 512 threads = 8 waves; wave w owns rows [bx*128 + w*16, +16) x BN cols.
// KPAD = per-dispatch K span; blockIdx.z selects the K-slice (koff = z*KPAD, B slabs offset).
// PART: write fp32 partials to F0[z*M*ldc + gr*ldc + gc] (no bias; combined later).
// Iteration: wait vmcnt(NA) [own stage(ck) done] -> s_barrier -> stage(ck+1) -> compute(ck).
template <int BN, int KPAD, int KS0, int KREAL, bool AFP32, bool RELU, bool PQ, bool PART>
__global__ __launch_bounds__(512, 4) void k_mm8(
    const void* __restrict__ A0v, const short* __restrict__ A1,
    const short* __restrict__ Bg, const float* __restrict__ bias,
    short* __restrict__ CH, int ldc,
    float* __restrict__ F0, float* __restrict__ F1, int splitN,
    int M, int N) {
    constexpr int NT = BN / 16;          // col tiles per wave
    constexpr int C = KPAD / 64;         // 64-wide k-chunks per dispatch slice
    constexpr int PT = (BN * 16) / 512;  // gload_lds issues per thread per chunk
    constexpr int SLAB = BN * 128;       // shorts per buffer
    constexpr int NA = AFP32 ? 4 : 0;    // A global loads per thread per chunk
    static_assert((BN * 16) % 512 == 0, "staging divisibility");
    static_assert(C >= 3, "peel structure needs >=3 chunks");
    __shared__ short Bs[2 * SLAB];
    int tid = threadIdx.x;
    int wave = tid >> 6, lane = tid & 63;
    int quad = lane >> 4, l16 = lane & 15;
    int colBase = blockIdx.y * BN;
    int koff = blockIdx.z * KPAD;
    int r0 = blockIdx.x * 128 + wave * 16 + l16;
    int r0c = min(r0, M - 1);
    const short* Bbase = Bg + ((size_t)blockIdx.y * gridDim.z + blockIdx.z) * (C * SLAB);

    f32x4 acc[NT];
#pragma unroll
    for (int n = 0; n < NT; ++n) acc[n] = (f32x4){0.f, 0.f, 0.f, 0.f};

    auto stageB = [&](int buf, int ck) {
        const short* src = Bbase + (size_t)ck * SLAB;
        short* db = Bs + buf * SLAB;
#pragma unroll
        for (int u = 0; u < PT; ++u) {
            int base = u * 512 + wave * 64;                 // wave-uniform chunk base
            gl16(src + (size_t)(base + lane) * 8, db + (size_t)base * 8);
        }
    };

    short8 aPre[AFP32 ? 2 : (2 * C)];
    short8 aCur[2];
    f32x4 fN[2][4];   // fp32 A double-buffer (2 chunks in flight)
    const float* Af = (const float*)A0v + (size_t)r0c * (size_t)KREAL;

    auto ldA32 = [&](int slot, int ck) {
#pragma unroll
        for (int s = 0; s < 2; ++s) {
            int kg = koff + ck * 64 + s * 32 + quad * 8;
            f32x4 f0 = {0.f, 0.f, 0.f, 0.f}, f1 = {0.f, 0.f, 0.f, 0.f};
            if (kg < KREAL) f0 = *(const f32x4*)(Af + kg);
            if (kg + 4 < KREAL) f1 = *(const f32x4*)(Af + kg + 4);
            fN[slot][s * 2] = f0;
            fN[slot][s * 2 + 1] = f1;
        }
    };
    auto cvtA = [&](int slot) {
#pragma unroll
        for (int s = 0; s < 2; ++s) {
            short8 a;
#pragma unroll
            for (int j = 0; j < 4; ++j) {
                a[j] = (short)f2bf(fN[slot][s * 2][j]);
                a[j + 4] = (short)f2bf(fN[slot][s * 2 + 1][j]);
            }
            aCur[s] = a;
        }
    };
    auto compute = [&](int ck) {
        const short* bb = Bs + (ck & 1) * SLAB;
#pragma unroll
        for (int s = 0; s < 2; ++s) {
            short8 a;
            if constexpr (AFP32) a = aCur[s];
            else                 a = aPre[ck * 2 + s];
#pragma unroll
            for (int n = 0; n < NT; ++n) {
                int r = n * 16 + l16;
                int ch = (s * 4 + quad) ^ (r & 7);
                short8 bh = *(const short8*)(bb + r * 128 + ch * 8);
                short8 bl = *(const short8*)(bb + r * 128 + (8 + ch) * 8);
                acc[n] = __builtin_amdgcn_mfma_f32_16x16x32_bf16(a, bh, acc[n], 0, 0, 0);
                acc[n] = __builtin_amdgcn_mfma_f32_16x16x32_bf16(a, bl, acc[n], 0, 0, 0);
            }
        }
    };

    // ---- prologue: stage(0) first, then A(0), A(1) (so vmcnt(NA) covers stage0+A0) ----
    if constexpr (!AFP32) {
        const short* A0 = (const short*)A0v;
#pragma unroll
        for (int c = 0; c < C; ++c) {
            const bool seg = (c * 64 >= KS0);
            const short* ap = seg ? A1 : A0;
            const int w = seg ? (KPAD - KS0) : KS0;
            const int col = c * 64 - (seg ? KS0 : 0);
#pragma unroll
            for (int s = 0; s < 2; ++s)
                aPre[c * 2 + s] =
                    *(const short8*)(ap + (size_t)r0c * w + col + s * 32 + quad * 8);
        }
    }
    stageB(0, 0);
    if constexpr (AFP32) { ldA32(0, 0); ldA32(1, 1); }

    // ---- main loop: wait(own stage ck) -> barrier -> stage(ck+1) -> compute(ck) ----
#pragma unroll
    for (int ck = 0; ck <= C - 2; ++ck) {
        asm volatile("s_waitcnt vmcnt(%0)" ::"n"(NA) : "memory");
        __builtin_amdgcn_s_barrier();
        __builtin_amdgcn_sched_barrier(0);
        stageB((ck + 1) & 1, ck + 1);
        if constexpr (AFP32) {
            cvtA(ck & 1);
            if (ck + 2 < C) ldA32(ck & 1, ck + 2);
        }
        compute(ck);
    }
    {   // ck = C-1: nothing issued after stage(C-1) -> full drain (only one in the loop)
        asm volatile("s_waitcnt vmcnt(0)" ::: "memory");
        __builtin_amdgcn_s_barrier();
        __builtin_amdgcn_sched_barrier(0);
        if constexpr (AFP32) cvtA((C - 1) & 1);
        compute(C - 1);
    }

    // ---- epilogue: C-layout col=lane&15, row=quad*4+reg ----
    int gr0 = blockIdx.x * 128 + wave * 16 + quad * 4;
#pragma unroll
    for (int n = 0; n < NT; ++n) {
        int gc = colBase + n * 16 + l16;
        if (gc >= N) continue;
        float b = (!PART && bias) ? bias[gc] : 0.f;
#pragma unroll
        for (int r = 0; r < 4; ++r) {
            int gr = gr0 + r;
            if (gr < M) {
                float v = acc[n][r] + b;
                if (RELU) v = fmaxf(v, 0.f);
                if constexpr (PART) {
                    F0[((size_t)blockIdx.z * M + gr) * ldc + gc] = v;
                } else if constexpr (PQ) {
                    if (gc < splitN) CH[(size_t)gr * ldc + gc] = (short)f2bf(v);
                    else             F0[(size_t)gr * (N - splitN) + (gc - splitN)] = v;
                } else {
                    if (CH) CH[(size_t)gr * ldc + gc] = (short)f2bf(v);
                    if (F0) {
                        if (gc < splitN) F0[(size_t)gr * splitN + gc] = v;
                        else             F1[(size_t)gr * (N - splitN) + (gc - splitN)] = v;
                    }
                }
            }
        }
    }
}

// ---- split-K combine: h0H = bf16(P[0] + P[1] + bias), 8 elems/thread ----
__global__ __launch_bounds__(256) void k_comb(
    const float* __restrict__ P, const float* __restrict__ bias,
    short* __restrict__ outH) {
    int idx = blockIdx.x * 256 + threadIdx.x;
    if (idx >= NN * 16) return;
    size_t off = (size_t)idx * 8;
    int col = (idx & 15) * 8;
    f32x4 a0 = *(const f32x4*)(P + off);
    f32x4 a1 = *(const f32x4*)(P + off + 4);
    f32x4 b0 = *(const f32x4*)(P + (size_t)NN * 128 + off);
    f32x4 b1 = *(const f32x4*)(P + (size_t)NN * 128 + off + 4);
    f32x4 c0 = *(const f32x4*)(bias + col);
    f32x4 c1 = *(const f32x4*)(bias + col + 4);
    short8 hv;
#pragma unroll
    for (int j = 0; j < 4; ++j) {
        hv[j] = (short)f2bf(a0[j] + b0[j] + c0[j]);
        hv[j + 4] = (short)f2bf(a1[j] + b1[j] + c1[j]);
    }
    *(short8*)(outH + off) = hv;
}

// ---------------- fused layer-3 aggregation + bias + residual + log_softmax ----------------
// pH: bf16 [NN][64] (cols 0-39 valid, rows 128B-aligned); q: fp32 [NN][40]
// 4-deep unrolled gather for MLP.
__global__ __launch_bounds__(256) void k_final(
    const short* __restrict__ pH, const float* __restrict__ q,
    const int* __restrict__ offs, const int* __restrict__ ssrc,
    const float* __restrict__ bl3, float* __restrict__ out) {
    int wid = (blockIdx.x * 256 + threadIdx.x) >> 6;
    int lane = threadIdx.x & 63;
    if (wid >= NN) return;
    bool act = lane < NCLS;
    int beg = offs[wid], end = offs[wid + 1];
    float a0 = 0.f, a1 = 0.f, a2 = 0.f, a3 = 0.f;
    int i = beg;
    for (; i + 3 < end; i += 4) {
        int s0 = ssrc[i], s1 = ssrc[i + 1], s2 = ssrc[i + 2], s3 = ssrc[i + 3];
        if (act) {
            a0 += bf2f((unsigned short)pH[(size_t)s0 * 64 + lane]);
            a1 += bf2f((unsigned short)pH[(size_t)s1 * 64 + lane]);
            a2 += bf2f((unsigned short)pH[(size_t)s2 * 64 + lane]);
            a3 += bf2f((unsigned short)pH[(size_t)s3 * 64 + lane]);
        }
    }
    for (; i < end; ++i) {
        int s0 = ssrc[i];
        if (act) a0 += bf2f((unsigned short)pH[(size_t)s0 * 64 + lane]);
    }
    float inv = 1.f / fmaxf((float)(end - beg), 1.f);
    float v = act ? ((a0 + a1) + (a2 + a3)) * inv + bl3[lane] + q[(size_t)wid * NCLS + lane]
                  : -INFINITY;
    float m = v;
#pragma unroll
    for (int off = 32; off > 0; off >>= 1) m = fmaxf(m, __shfl_xor(m, off));
    float e = act ? expf(v - m) : 0.f;
    float s = e;
#pragma unroll
    for (int off = 32; off > 0; off >>= 1) s += __shfl_xor(s, off);
    float ls = logf(s);
    if (act) out[(size_t)wid * NCLS + lane] = v - m - ls;
}

extern "C" void kernel_launch(void* const* d_in, const int* in_sizes, int n_in,
                              void* d_out, int out_size, void* d_ws, size_t ws_size,
                              hipStream_t stream) {
    const float* x    = (const float*)d_in[0];
    const int*   ei   = (const int*)d_in[1];
    const int*   esrc = ei;        // row 0: src
    const int*   edst = ei + NE;   // row 1: dst
    const float* W_map = (const float*)d_in[2];
    const float* b_map = (const float*)d_in[3];
    const float* Wl1   = (const float*)d_in[4];
    const float* bl1   = (const float*)d_in[5];
    const float* Wr1   = (const float*)d_in[6];
    const float* Wl2   = (const float*)d_in[7];
    const float* bl2   = (const float*)d_in[8];
    const float* Wr2   = (const float*)d_in[9];
    const float* Wl3   = (const float*)d_in[10];
    const float* bl3   = (const float*)d_in[11];
    const float* Wr3   = (const float*)d_in[12];
    float* out = (float*)d_out;

    char* ws = (char*)d_ws;
    short* h0H = (short*)ws; ws += (size_t)NN * 128 * 2;
    short* m0H = (short*)ws; ws += (size_t)NN * 128 * 2;
    short* h1H = (short*)ws; ws += (size_t)NN * 128 * 2;
    short* m1H = (short*)ws; ws += (size_t)NN * 128 * 2;
    short* h2H = (short*)ws; ws += (size_t)NN * 256 * 2;
    short* pH  = (short*)ws; ws += (size_t)NN * 64 * 2;   // bf16, rows padded to 64
    float* q   = (float*)ws; ws += (size_t)NN * NCLS * 4;
    short* wt  = (short*)ws; ws += (size_t)376832 * 2;
    int* deg    = (int*)ws;  ws += (size_t)NN * 4;
    int* offs   = (int*)ws;  ws += (size_t)(NN + 2) * 4;
    int* cursor = (int*)ws;  ws += (size_t)NN * 4;
    int* ssrc   = (int*)ws;  ws += (size_t)NE * 4;
    int* bsum   = (int*)ws;  ws += (size_t)256 * 4;
    int* bpre   = (int*)ws;  ws += (size_t)256 * 4;
    float* pk   = (float*)ws; ws += (size_t)2 * NN * 128 * 4;  // split-K partials

    // blocked pre-swizzled weight buffers: [yb][ck64][BN][128], BN=128 (b3w: 96)
    short* m_w  = wt + 0;       // 1yb * 8ck * 128 * 128 = 131072
    short* b1w  = wt + 131072;  // 1yb * 4ck * 128 * 128 = 65536
    short* b2w  = wt + 196608;  // 2yb * 4ck * 128 * 128 = 131072
    short* b3w  = wt + 327680;  // 1yb * 4ck *  96 * 128 = 49152  (total 376832)

    // --- weight split/transpose (tiny) ---
    (void)hipMemsetAsync(b3w, 0, (size_t)49152 * 2, stream);  // zero pad rows 80-95
    k_wsplit<<<(128 * 512 + 255) / 256, 256, 0, stream>>>(W_map, m_w, FIN, 128, 512, 128, 0, 0, 9);
    k_wsplit<<<(128 * 128 + 255) / 256, 256, 0, stream>>>(Wr1, b1w, 128, 128, 256, 128, 0, 0, 7);
    k_wsplit<<<(128 * 128 + 255) / 256, 256, 0, stream>>>(Wl1, b1w, 128, 128, 256, 128, 128, 0, 7);
    k_wsplit<<<(256 * 128 + 255) / 256, 256, 0, stream>>>(Wr2, b2w, 128, 256, 256, 128, 0, 0, 7);
    k_wsplit<<<(256 * 128 + 255) / 256, 256, 0, stream>>>(Wl2, b2w, 128, 256, 256, 128, 128, 0, 7);
    k_wsplit<<<(40 * 256 + 255) / 256, 256, 0, stream>>>(Wl3, b3w, 256, 40, 256, 96, 0, 0, 8);
    k_wsplit<<<(40 * 256 + 255) / 256, 256, 0, stream>>>(Wr3, b3w, 256, 40, 256, 96, 0, 40, 8);

    // --- CSR bucketing of edges by dst (two-level scan) ---
    (void)hipMemsetAsync(deg, 0, (size_t)NN * 4, stream);
    k_count<<<(NE + 255) / 256, 256, 0, stream>>>(edst, deg);
    k_scan1<<<NB, 256, 0, stream>>>(deg, offs, bsum);
    k_scan2<<<1, 256, 0, stream>>>(bsum, bpre, offs);
    k_scan3<<<NB, 256, 0, stream>>>(offs, bpre, cursor);
    k_scatter<<<(NE + 255) / 256, 256, 0, stream>>>(esrc, edst, cursor, ssrc);

    const int g128 = (NN + 127) / 128;  // 391
    const int aggBlocks = (NN * 64) / 256;

    // h0 = x @ W_map + b_map  (split-K=2: fp32 partials, then combine)
    k_mm8<128, 256, 256, FIN, true, false, false, true><<<dim3(g128, 1, 2), 512, 0, stream>>>(
        (const void*)x, nullptr, m_w, nullptr,
        nullptr, 128, pk, nullptr, 0, NN, 128);
    k_comb<<<(NN * 16 + 255) / 256, 256, 0, stream>>>(pk, b_map, h0H);

    // mean(h0) -> m0H
    k_aggb<<<aggBlocks, 256, 0, stream>>>(h0H, offs, ssrc, m0H);

    // h1 = relu([h0|mean] @ [Wr1;Wl1] + bl1) -> h1H
    k_mm8<128, 256, 128, 256, false, true, false, false><<<dim3(g128, 1), 512, 0, stream>>>(
        (const void*)h0H, m0H, b1w, bl1,
        h1H, 128, nullptr, nullptr, 0, NN, 128);

    // mean(h1) -> m1H
    k_aggb<<<aggBlocks, 256, 0, stream>>>(h1H, offs, ssrc, m1H);

    // h2 = relu([h1|mean] @ [Wr2;Wl2] + bl2) -> h2H [NN][256]
    k_mm8<128, 256, 128, 256, false, true, false, false><<<dim3(g128, 2), 512, 0, stream>>>(
        (const void*)h1H, m1H, b2w, bl2,
        h2H, 256, nullptr, nullptr, 0, NN, 256);

    // [p|q] = h2 @ [Wl3|Wr3] (BN padded to 96): cols 0-39 -> pH (bf16, ldc=64), 40-79 -> q
    k_mm8<96, 256, 256, 256, false, false, true, false><<<dim3(g128, 1), 512, 0, stream>>>(
        (const void*)h2H, nullptr, b3w, nullptr,
        pH, 64, q, nullptr, NCLS, NN, 80);

    // fused: logits = mean_agg(pH) + bl3 + q; log_softmax -> out
    k_final<<<aggBlocks, 256, 0, stream>>>(pH, q, offs, ssrc, bl3, out);
}

// Round 11
// 451.569 us; speedup vs baseline: 1.0879x; 1.0879x over previous
//
#include <hip/hip_runtime.h>
#include <math.h>

#define NN 50000
#define NE 800000
#define FIN 500
#define NCLS 40
#define NB 196  // scan blocks = ceil(NN/256)

typedef short short8 __attribute__((ext_vector_type(8)));
typedef float f32x4 __attribute__((ext_vector_type(4)));

__device__ __forceinline__ unsigned short f2bf(float f) {
    unsigned u = __float_as_uint(f);
    unsigned r = (u + 0x7FFFu + ((u >> 16) & 1u)) >> 16;
    return (unsigned short)r;
}
__device__ __forceinline__ float bf2f(unsigned short h) {
    return __uint_as_float(((unsigned)h) << 16);
}

// global -> LDS direct copy, 16B per lane; LDS dest is wave-uniform base + lane*16
typedef const __attribute__((address_space(1))) void gv1;
typedef __attribute__((address_space(3))) void lv3;
__device__ __forceinline__ void gl16(const void* g, void* l) {
    __builtin_amdgcn_global_load_lds((gv1*)g, (lv3*)l, 16, 0, 0);
}

// ---- weight split+transpose into blocked, pre-swizzled layout ----
// dst layout: [yb][ck64][r (0..BN-1)][16 x 16B-chunks: hi 0-7, lo 8-15, chunk^ (r&7)]
__global__ void k_wsplit(const float* __restrict__ W, short* __restrict__ dst,
                         int Ksrc, int Ncols, int Kpad, int BN, int koff,
                         int noff, int llog) {
    int i = blockIdx.x * 256 + threadIdx.x;
    int len = 1 << llog;
    if (i >= Ncols * len) return;
    int n = i >> llog, kk = i & (len - 1);
    float v = (kk < Ksrc) ? W[(size_t)kk * Ncols + n] : 0.f;
    unsigned short hi = f2bf(v);
    float lo = v - bf2f(hi);
    int nd = noff + n, kd = koff + kk;
    int yb = nd / BN, r = nd % BN;
    int ck = kd >> 6, kin = kd & 63;
    int c16h = (kin >> 3) ^ (r & 7);
    size_t rowb = (((size_t)yb * (Kpad >> 6) + ck) * BN + r) * 128;
    dst[rowb + c16h * 8 + (kin & 7)] = (short)hi;
    dst[rowb + (8 + c16h) * 8 + (kin & 7)] = (short)f2bf(lo);
}

// ---------------- counting sort of edges by dst ----------------
__global__ void k_count(const int* __restrict__ dst, int* __restrict__ deg) {
    int e = blockIdx.x * blockDim.x + threadIdx.x;
    if (e < NE) atomicAdd(&deg[dst[e]], 1);
}

__global__ void k_scan1(const int* __restrict__ deg, int* __restrict__ offs,
                        int* __restrict__ bsum) {
    __shared__ int sm[256];
    int tid = threadIdx.x;
    int i = blockIdx.x * 256 + tid;
    int v = (i < NN) ? deg[i] : 0;
    sm[tid] = v;
    __syncthreads();
    for (int off = 1; off < 256; off <<= 1) {
        int t = (tid >= off) ? sm[tid - off] : 0;
        __syncthreads();
        sm[tid] += t;
        __syncthreads();
    }
    if (i < NN) offs[i] = sm[tid] - v;
    if (tid == 255) bsum[blockIdx.x] = sm[255];
}

__global__ void k_scan2(const int* __restrict__ bsum, int* __restrict__ bpre,
                        int* __restrict__ offs) {
    __shared__ int sm[256];
    int tid = threadIdx.x;
    int v = (tid < NB) ? bsum[tid] : 0;
    sm[tid] = v;
    __syncthreads();
    for (int off = 1; off < 256; off <<= 1) {
        int t = (tid >= off) ? sm[tid - off] : 0;
        __syncthreads();
        sm[tid] += t;
        __syncthreads();
    }
    if (tid < NB) bpre[tid] = sm[tid] - v;
    if (tid == 255) offs[NN] = sm[255];
}

__global__ void k_scan3(int* __restrict__ offs, const int* __restrict__ bpre,
                        int* __restrict__ cursor) {
    int i = blockIdx.x * 256 + threadIdx.x;
    if (i < NN) {
        int v = offs[i] + bpre[blockIdx.x];
        offs[i] = v;
        cursor[i] = v;
    }
}

__global__ void k_scatter(const int* __restrict__ src, const int* __restrict__ dst,
                          int* __restrict__ cursor, int* __restrict__ ssrc) {
    int e = blockIdx.x * blockDim.x + threadIdx.x;
    if (e < NE) {
        int p = atomicAdd(&cursor[dst[e]], 1);
        ssrc[p] = src[e];
    }
}

// ---- mean aggregation from bf16 table [NN][128] -> bf16 mean plane [NN][128] ----
// one wave per node; 16-lane subwave per edge (16B/lane).
// Fully predicated 4-deep gather: index clamped to end-1, contribution weighted by
// (idx<end) -> every iteration keeps 4 row-gathers in flight even for degree<16 nodes
// (Poisson(16) degree distribution: ~40% of nodes never entered the old 4-deep loop).
__global__ __launch_bounds__(256) void k_aggb(
    const short* __restrict__ hb, const int* __restrict__ offs,
    const int* __restrict__ ssrc, short* __restrict__ mH) {
    int wid = (blockIdx.x * 256 + threadIdx.x) >> 6;
    int lane = threadIdx.x & 63;
    if (wid >= NN) return;
    int sub = lane >> 4, l16 = lane & 15;
    int beg = offs[wid], end = offs[wid + 1];
    f32x4 a0 = {0.f, 0.f, 0.f, 0.f}, a1 = {0.f, 0.f, 0.f, 0.f};
    for (int i = beg + sub; i < end; i += 16) {
        int i1 = i + 4, i2 = i + 8, i3 = i + 12;
        int em1 = end - 1;
        int s0 = ssrc[i];
        int s1 = ssrc[min(i1, em1)];
        int s2 = ssrc[min(i2, em1)];
        int s3 = ssrc[min(i3, em1)];
        float w1 = (i1 < end) ? 1.f : 0.f;
        float w2 = (i2 < end) ? 1.f : 0.f;
        float w3 = (i3 < end) ? 1.f : 0.f;
        short8 v0 = *(const short8*)(hb + (size_t)s0 * 128 + l16 * 8);
        short8 v1 = *(const short8*)(hb + (size_t)s1 * 128 + l16 * 8);
        short8 v2 = *(const short8*)(hb + (size_t)s2 * 128 + l16 * 8);
        short8 v3 = *(const short8*)(hb + (size_t)s3 * 128 + l16 * 8);
#pragma unroll
        for (int j = 0; j < 4; ++j) {
            a0[j] += (bf2f((unsigned short)v0[j]) + w1 * bf2f((unsigned short)v1[j])) +
                     (w2 * bf2f((unsigned short)v2[j]) + w3 * bf2f((unsigned short)v3[j]));
            a1[j] += (bf2f((unsigned short)v0[j + 4]) + w1 * bf2f((unsigned short)v1[j + 4])) +
                     (w2 * bf2f((unsigned short)v2[j + 4]) + w3 * bf2f((unsigned short)v3[j + 4]));
        }
    }
#pragma unroll
    for (int j = 0; j < 4; ++j) {
        a0[j] += __shfl_xor(a0[j], 16);
        a0[j] += __shfl_xor(a0[j], 32);
        a1[j] += __shfl_xor(a1[j], 16);
        a1[j] += __shfl_xor(a1[j], 32);
    }
    if (sub == 0) {
        float inv = 1.f / fmaxf((float)(end - beg), 1.f);
        a0 *= inv; a1 *= inv;
        short8 hv;
#pragma unroll
        for (int j = 0; j < 4; ++j) {
            hv[j] = (short)f2bf(a0[j]);
            hv[j + 4] = (short)f2bf(a1[j]);
        }
        *(short8*)(mH + (size_t)wid * 128 + l16 * 8) = hv;
    }
}

// ---------------- MFMA GEMM: counted-vmcnt pipeline, race-free ordering ----------------
// 512 threads = 8 waves; wave w owns rows [bx*128 + w*16, +16) x BN cols.
// Per iteration ck:
//   s_waitcnt vmcnt(NA)  // own stage(ck) [+A(ck)] complete
//   s_barrier            // all waves' stage(ck) visible AND compute(ck-1) reads consumed
//   stage(ck+1)          // safe: overwrites buffer nobody reads anymore
//   cvtA / ldA(ck+2)
//   compute(ck)
template <int BN, int KPAD, int KS0, int KREAL, bool AFP32, bool RELU, bool PQ>
__global__ __launch_bounds__(512, 4) void k_mm8(
    const void* __restrict__ A0v, const short* __restrict__ A1,
    const short* __restrict__ Bg, const float* __restrict__ bias,
    short* __restrict__ CH, int ldc,
    float* __restrict__ F0, float* __restrict__ F1, int splitN,
    int M, int N) {
    constexpr int NT = BN / 16;          // col tiles per wave
    constexpr int C = KPAD / 64;         // 64-wide k-chunks
    constexpr int PT = (BN * 16) / 512;  // gload_lds issues per thread per chunk
    constexpr int SLAB = BN * 128;       // shorts per buffer
    constexpr int NA = AFP32 ? 4 : 0;    // A global loads per thread per chunk
    static_assert((BN * 16) % 512 == 0, "staging divisibility");
    static_assert(C >= 3, "peel structure needs >=3 chunks");
    __shared__ short Bs[2 * SLAB];
    int tid = threadIdx.x;
    int wave = tid >> 6, lane = tid & 63;
    int quad = lane >> 4, l16 = lane & 15;
    int colBase = blockIdx.y * BN;
    int r0 = blockIdx.x * 128 + wave * 16 + l16;
    int r0c = min(r0, M - 1);
    const short* Bbase = Bg + (size_t)blockIdx.y * (C * SLAB);

    f32x4 acc[NT];
#pragma unroll
    for (int n = 0; n < NT; ++n) acc[n] = (f32x4){0.f, 0.f, 0.f, 0.f};

    auto stageB = [&](int buf, int ck) {
        const short* src = Bbase + (size_t)ck * SLAB;
        short* db = Bs + buf * SLAB;
#pragma unroll
        for (int u = 0; u < PT; ++u) {
            int base = u * 512 + wave * 64;                 // wave-uniform chunk base
            gl16(src + (size_t)(base + lane) * 8, db + (size_t)base * 8);
        }
    };

    short8 aPre[AFP32 ? 2 : (2 * C)];
    short8 aCur[2];
    f32x4 fN[2][4];   // fp32 A double-buffer (2 chunks in flight)
    const float* Af = (const float*)A0v + (size_t)r0c * (size_t)KREAL;

    auto ldA32 = [&](int slot, int ck) {
#pragma unroll
        for (int s = 0; s < 2; ++s) {
            int kg = ck * 64 + s * 32 + quad * 8;
            f32x4 f0 = {0.f, 0.f, 0.f, 0.f}, f1 = {0.f, 0.f, 0.f, 0.f};
            if (kg < KREAL) f0 = *(const f32x4*)(Af + kg);
            if (kg + 4 < KREAL) f1 = *(const f32x4*)(Af + kg + 4);
            fN[slot][s * 2] = f0;
            fN[slot][s * 2 + 1] = f1;
        }
    };
    auto cvtA = [&](int slot) {
#pragma unroll
        for (int s = 0; s < 2; ++s) {
            short8 a;
#pragma unroll
            for (int j = 0; j < 4; ++j) {
                a[j] = (short)f2bf(fN[slot][s * 2][j]);
                a[j + 4] = (short)f2bf(fN[slot][s * 2 + 1][j]);
            }
            aCur[s] = a;
        }
    };
    auto compute = [&](int ck) {
        const short* bb = Bs + (ck & 1) * SLAB;
#pragma unroll
        for (int s = 0; s < 2; ++s) {
            short8 a;
            if constexpr (AFP32) a = aCur[s];
            else                 a = aPre[ck * 2 + s];
#pragma unroll
            for (int n = 0; n < NT; ++n) {
                int r = n * 16 + l16;
                int ch = (s * 4 + quad) ^ (r & 7);
                short8 bh = *(const short8*)(bb + r * 128 + ch * 8);
                short8 bl = *(const short8*)(bb + r * 128 + (8 + ch) * 8);
                acc[n] = __builtin_amdgcn_mfma_f32_16x16x32_bf16(a, bh, acc[n], 0, 0, 0);
                acc[n] = __builtin_amdgcn_mfma_f32_16x16x32_bf16(a, bl, acc[n], 0, 0, 0);
            }
        }
    };

    // ---- prologue: stage(0) first, then A(0), A(1) (so vmcnt(NA) covers stage0+A0) ----
    if constexpr (!AFP32) {
        const short* A0 = (const short*)A0v;
#pragma unroll
        for (int c = 0; c < C; ++c) {
            const bool seg = (c * 64 >= KS0);
            const short* ap = seg ? A1 : A0;
            const int w = seg ? (KPAD - KS0) : KS0;
            const int col = c * 64 - (seg ? KS0 : 0);
#pragma unroll
            for (int s = 0; s < 2; ++s)
                aPre[c * 2 + s] =
                    *(const short8*)(ap + (size_t)r0c * w + col + s * 32 + quad * 8);
        }
    }
    stageB(0, 0);
    if constexpr (AFP32) { ldA32(0, 0); ldA32(1, 1); }

    // ---- main loop: wait(own stage ck) -> barrier -> stage(ck+1) -> compute(ck) ----
#pragma unroll
    for (int ck = 0; ck <= C - 2; ++ck) {
        asm volatile("s_waitcnt vmcnt(%0)" ::"n"(NA) : "memory");
        __builtin_amdgcn_s_barrier();
        __builtin_amdgcn_sched_barrier(0);
        stageB((ck + 1) & 1, ck + 1);
        if constexpr (AFP32) {
            cvtA(ck & 1);
            if (ck + 2 < C) ldA32(ck & 1, ck + 2);
        }
        compute(ck);
    }
    {   // ck = C-1: nothing issued after stage(C-1) -> full drain (only one in the loop)
        asm volatile("s_waitcnt vmcnt(0)" ::: "memory");
        __builtin_amdgcn_s_barrier();
        __builtin_amdgcn_sched_barrier(0);
        if constexpr (AFP32) cvtA((C - 1) & 1);
        compute(C - 1);
    }

    // ---- epilogue: C-layout col=lane&15, row=quad*4+reg ----
    int gr0 = blockIdx.x * 128 + wave * 16 + quad * 4;
#pragma unroll
    for (int n = 0; n < NT; ++n) {
        int gc = colBase + n * 16 + l16;
        if (gc >= N) continue;
        float b = bias ? bias[gc] : 0.f;
#pragma unroll
        for (int r = 0; r < 4; ++r) {
            int gr = gr0 + r;
            if (gr < M) {
                float v = acc[n][r] + b;
                if (RELU) v = fmaxf(v, 0.f);
                if constexpr (PQ) {
                    if (gc < splitN) CH[(size_t)gr * ldc + gc] = (short)f2bf(v);
                    else             F0[(size_t)gr * (N - splitN) + (gc - splitN)] = v;
                } else {
                    if (CH) CH[(size_t)gr * ldc + gc] = (short)f2bf(v);
                    if (F0) {
                        if (gc < splitN) F0[(size_t)gr * splitN + gc] = v;
                        else             F1[(size_t)gr * (N - splitN) + (gc - splitN)] = v;
                    }
                }
            }
        }
    }
}

// ---------------- fused layer-3 aggregation + bias + residual + log_softmax ----------------
// pH: bf16 [NN][64] (cols 0-39 valid, rows 128B-aligned); q: fp32 [NN][40]
// Fully predicated 4-deep gather (clamped index + 0/1 weight): no serial tail.
__global__ __launch_bounds__(256) void k_final(
    const short* __restrict__ pH, const float* __restrict__ q,
    const int* __restrict__ offs, const int* __restrict__ ssrc,
    const float* __restrict__ bl3, float* __restrict__ out) {
    int wid = (blockIdx.x * 256 + threadIdx.x) >> 6;
    int lane = threadIdx.x & 63;
    if (wid >= NN) return;
    bool act = lane < NCLS;
    int beg = offs[wid], end = offs[wid + 1];
    float a0 = 0.f, a1 = 0.f, a2 = 0.f, a3 = 0.f;
    for (int i = beg; i < end; i += 4) {
        int em1 = end - 1;
        int s0 = ssrc[i];
        int s1 = ssrc[min(i + 1, em1)];
        int s2 = ssrc[min(i + 2, em1)];
        int s3 = ssrc[min(i + 3, em1)];
        float w1 = (i + 1 < end) ? 1.f : 0.f;
        float w2 = (i + 2 < end) ? 1.f : 0.f;
        float w3 = (i + 3 < end) ? 1.f : 0.f;
        if (act) {
            a0 += bf2f((unsigned short)pH[(size_t)s0 * 64 + lane]);
            a1 += w1 * bf2f((unsigned short)pH[(size_t)s1 * 64 + lane]);
            a2 += w2 * bf2f((unsigned short)pH[(size_t)s2 * 64 + lane]);
            a3 += w3 * bf2f((unsigned short)pH[(size_t)s3 * 64 + lane]);
        }
    }
    float inv = 1.f / fmaxf((float)(end - beg), 1.f);
    float v = act ? ((a0 + a1) + (a2 + a3)) * inv + bl3[lane] + q[(size_t)wid * NCLS + lane]
                  : -INFINITY;
    float m = v;
#pragma unroll
    for (int off = 32; off > 0; off >>= 1) m = fmaxf(m, __shfl_xor(m, off));
    float e = act ? expf(v - m) : 0.f;
    float s = e;
#pragma unroll
    for (int off = 32; off > 0; off >>= 1) s += __shfl_xor(s, off);
    float ls = logf(s);
    if (act) out[(size_t)wid * NCLS + lane] = v - m - ls;
}

extern "C" void kernel_launch(void* const* d_in, const int* in_sizes, int n_in,
                              void* d_out, int out_size, void* d_ws, size_t ws_size,
                              hipStream_t stream) {
    const float* x    = (const float*)d_in[0];
    const int*   ei   = (const int*)d_in[1];
    const int*   esrc = ei;        // row 0: src
    const int*   edst = ei + NE;   // row 1: dst
    const float* W_map = (const float*)d_in[2];
    const float* b_map = (const float*)d_in[3];
    const float* Wl1   = (const float*)d_in[4];
    const float* bl1   = (const float*)d_in[5];
    const float* Wr1   = (const float*)d_in[6];
    const float* Wl2   = (const float*)d_in[7];
    const float* bl2   = (const float*)d_in[8];
    const float* Wr2   = (const float*)d_in[9];
    const float* Wl3   = (const float*)d_in[10];
    const float* bl3   = (const float*)d_in[11];
    const float* Wr3   = (const float*)d_in[12];
    float* out = (float*)d_out;

    char* ws = (char*)d_ws;
    short* h0H = (short*)ws; ws += (size_t)NN * 128 * 2;
    short* m0H = (short*)ws; ws += (size_t)NN * 128 * 2;
    short* h1H = (short*)ws; ws += (size_t)NN * 128 * 2;
    short* m1H = (short*)ws; ws += (size_t)NN * 128 * 2;
    short* h2H = (short*)ws; ws += (size_t)NN * 256 * 2;
    short* pH  = (short*)ws; ws += (size_t)NN * 64 * 2;   // bf16, rows padded to 64
    float* q   = (float*)ws; ws += (size_t)NN * NCLS * 4;
    short* wt  = (short*)ws; ws += (size_t)376832 * 2;
    int* deg    = (int*)ws;  ws += (size_t)NN * 4;
    int* offs   = (int*)ws;  ws += (size_t)(NN + 2) * 4;
    int* cursor = (int*)ws;  ws += (size_t)NN * 4;
    int* ssrc   = (int*)ws;  ws += (size_t)NE * 4;
    int* bsum   = (int*)ws;  ws += (size_t)256 * 4;
    int* bpre   = (int*)ws;  ws += (size_t)256 * 4;

    // blocked pre-swizzled weight buffers: [yb][ck64][BN][128], BN=128 (b3w: 96)
    short* m_w  = wt + 0;       // 1yb * 8ck * 128 * 128 = 131072
    short* b1w  = wt + 131072;  // 1yb * 4ck * 128 * 128 = 65536
    short* b2w  = wt + 196608;  // 2yb * 4ck * 128 * 128 = 131072
    short* b3w  = wt + 327680;  // 1yb * 4ck *  96 * 128 = 49152  (total 376832)

    // --- weight split/transpose (tiny) ---
    (void)hipMemsetAsync(b3w, 0, (size_t)49152 * 2, stream);  // zero pad rows 80-95
    k_wsplit<<<(128 * 512 + 255) / 256, 256, 0, stream>>>(W_map, m_w, FIN, 128, 512, 128, 0, 0, 9);
    k_wsplit<<<(128 * 128 + 255) / 256, 256, 0, stream>>>(Wr1, b1w, 128, 128, 256, 128, 0, 0, 7);
    k_wsplit<<<(128 * 128 + 255) / 256, 256, 0, stream>>>(Wl1, b1w, 128, 128, 256, 128, 128, 0, 7);
    k_wsplit<<<(256 * 128 + 255) / 256, 256, 0, stream>>>(Wr2, b2w, 128, 256, 256, 128, 0, 0, 7);
    k_wsplit<<<(256 * 128 + 255) / 256, 256, 0, stream>>>(Wl2, b2w, 128, 256, 256, 128, 128, 0, 7);
    k_wsplit<<<(40 * 256 + 255) / 256, 256, 0, stream>>>(Wl3, b3w, 256, 40, 256, 96, 0, 0, 8);
    k_wsplit<<<(40 * 256 + 255) / 256, 256, 0, stream>>>(Wr3, b3w, 256, 40, 256, 96, 0, 40, 8);

    // --- CSR bucketing of edges by dst (two-level scan) ---
    (void)hipMemsetAsync(deg, 0, (size_t)NN * 4, stream);
    k_count<<<(NE + 255) / 256, 256, 0, stream>>>(edst, deg);
    k_scan1<<<NB, 256, 0, stream>>>(deg, offs, bsum);
    k_scan2<<<1, 256, 0, stream>>>(bsum, bpre, offs);
    k_scan3<<<NB, 256, 0, stream>>>(offs, bpre, cursor);
    k_scatter<<<(NE + 255) / 256, 256, 0, stream>>>(esrc, edst, cursor, ssrc);

    const int g128 = (NN + 127) / 128;  // 391
    const int aggBlocks = (NN * 64) / 256;

    // h0 = x @ W_map + b_map -> h0H [NN][128] bf16
    k_mm8<128, 512, 512, FIN, true, false, false><<<dim3(g128, 1), 512, 0, stream>>>(
        (const void*)x, nullptr, m_w, b_map,
        h0H, 128, nullptr, nullptr, 0, NN, 128);

    // mean(h0) -> m0H
    k_aggb<<<aggBlocks, 256, 0, stream>>>(h0H, offs, ssrc, m0H);

    // h1 = relu([h0|mean] @ [Wr1;Wl1] + bl1) -> h1H
    k_mm8<128, 256, 128, 256, false, true, false><<<dim3(g128, 1), 512, 0, stream>>>(
        (const void*)h0H, m0H, b1w, bl1,
        h1H, 128, nullptr, nullptr, 0, NN, 128);

    // mean(h1) -> m1H
    k_aggb<<<aggBlocks, 256, 0, stream>>>(h1H, offs, ssrc, m1H);

    // h2 = relu([h1|mean] @ [Wr2;Wl2] + bl2) -> h2H [NN][256]
    k_mm8<128, 256, 128, 256, false, true, false><<<dim3(g128, 2), 512, 0, stream>>>(
        (const void*)h1H, m1H, b2w, bl2,
        h2H, 256, nullptr, nullptr, 0, NN, 256);

    // [p|q] = h2 @ [Wl3|Wr3] (BN padded to 96): cols 0-39 -> pH (bf16, ldc=64), 40-79 -> q
    k_mm8<96, 256, 256, 256, false, false, true><<<dim3(g128, 1), 512, 0, stream>>>(
        (const void*)h2H, nullptr, b3w, nullptr,
        pH, 64, q, nullptr, NCLS, NN, 80);

    // fused: logits = mean_agg(pH) + bl3 + q; log_softmax -> out
    k_final<<<aggBlocks, 256, 0, stream>>>(pH, q, offs, ssrc, bl3, out);
}

// Round 12
// 413.122 us; speedup vs baseline: 1.1892x; 1.0931x over previous
//
#include <hip/hip_runtime.h>
#include <math.h>

#define NN 50000
#define NE 800000
#define FIN 500
#define NCLS 40
#define NB 196   // scan blocks = ceil(NN/256)
#define G0 391   // GEMM row blocks = ceil(NN/128)
#define CNTB 1563 // count/scatter blocks = ceil(NE/512)
#define WSE 192512 // fused wsplit total elements

typedef short short8 __attribute__((ext_vector_type(8)));
typedef float f32x4 __attribute__((ext_vector_type(4)));

__device__ __forceinline__ unsigned short f2bf(float f) {
    unsigned u = __float_as_uint(f);
    unsigned r = (u + 0x7FFFu + ((u >> 16) & 1u)) >> 16;
    return (unsigned short)r;
}
__device__ __forceinline__ float bf2f(unsigned short h) {
    return __uint_as_float(((unsigned)h) << 16);
}

// global -> LDS direct copy, 16B per lane; LDS dest is wave-uniform base + lane*16
typedef const __attribute__((address_space(1))) void gv1;
typedef __attribute__((address_space(3))) void lv3;
__device__ __forceinline__ void gl16(const void* g, void* l) {
    __builtin_amdgcn_global_load_lds((gv1*)g, (lv3*)l, 16, 0, 0);
}

// ---- weight split+transpose into blocked, pre-swizzled layout ----
// dst layout: [yb][ck64][r (0..BN-1)][16 x 16B-chunks: hi 0-7, lo 8-15, chunk^ (r&7)]
__device__ __forceinline__ void wsplit_one(
    const float* __restrict__ W, short* __restrict__ dst,
    int Ksrc, int Ncols, int Kpad, int BN, int koff, int noff, int llog, int i) {
    int n = i >> llog, kk = i & ((1 << llog) - 1);
    float v = (kk < Ksrc) ? W[(size_t)kk * Ncols + n] : 0.f;
    unsigned short hi = f2bf(v);
    float lo = v - bf2f(hi);
    int nd = noff + n, kd = koff + kk;
    int yb = nd / BN, r = nd % BN;
    int ck = kd >> 6, kin = kd & 63;
    int c16h = (kin >> 3) ^ (r & 7);
    size_t rowb = (((size_t)yb * (Kpad >> 6) + ck) * BN + r) * 128;
    dst[rowb + c16h * 8 + (kin & 7)] = (short)hi;
    dst[rowb + (8 + c16h) * 8 + (kin & 7)] = (short)f2bf(lo);
}

// ---- mega1: edge-degree count (atomics) + all weight splits + b3w pad zero ----
__global__ __launch_bounds__(512) void k_mega1(
    const int* __restrict__ edst, int* __restrict__ deg,
    const float* __restrict__ W_map,
    const float* __restrict__ Wr1, const float* __restrict__ Wl1,
    const float* __restrict__ Wr2, const float* __restrict__ Wl2,
    const float* __restrict__ Wl3, const float* __restrict__ Wr3,
    short* __restrict__ m_w, short* __restrict__ b1w,
    short* __restrict__ b2w, short* __restrict__ b3w) {
    int tid = threadIdx.x;
    if (blockIdx.x < CNTB) {
        int e = blockIdx.x * 512 + tid;
        if (e < NE) atomicAdd(&deg[edst[e]], 1);
        return;
    }
    int idx = (blockIdx.x - CNTB) * 512 + tid;
    if (idx < 65536)       wsplit_one(W_map, m_w, FIN, 128, 512, 128, 0, 0, 9, idx);
    else if (idx < 81920)  wsplit_one(Wr1, b1w, 128, 128, 256, 128, 0, 0, 7, idx - 65536);
    else if (idx < 98304)  wsplit_one(Wl1, b1w, 128, 128, 256, 128, 128, 0, 7, idx - 81920);
    else if (idx < 131072) wsplit_one(Wr2, b2w, 128, 256, 256, 128, 0, 0, 7, idx - 98304);
    else if (idx < 163840) wsplit_one(Wl2, b2w, 128, 256, 256, 128, 128, 0, 7, idx - 131072);
    else if (idx < 174080) wsplit_one(Wl3, b3w, 256, 40, 256, 96, 0, 0, 8, idx - 163840);
    else if (idx < 184320) wsplit_one(Wr3, b3w, 256, 40, 256, 96, 0, 40, 8, idx - 174080);
    else if (idx < WSE) {  // zero b3w pad rows 80-95 (all 4 ck)
        int j = idx - 184320;
        int ck = j >> 11, rem = j & 2047;
        int r = 80 + (rem >> 7), c = rem & 127;
        b3w[((size_t)(ck * 96 + r)) * 128 + c] = 0;
    }
}

// ---------------- two-level scan of degrees ----------------
__global__ void k_scan1(const int* __restrict__ deg, int* __restrict__ offs,
                        int* __restrict__ bsum) {
    __shared__ int sm[256];
    int tid = threadIdx.x;
    int i = blockIdx.x * 256 + tid;
    int v = (i < NN) ? deg[i] : 0;
    sm[tid] = v;
    __syncthreads();
    for (int off = 1; off < 256; off <<= 1) {
        int t = (tid >= off) ? sm[tid - off] : 0;
        __syncthreads();
        sm[tid] += t;
        __syncthreads();
    }
    if (i < NN) offs[i] = sm[tid] - v;
    if (tid == 255) bsum[blockIdx.x] = sm[255];
}

__global__ void k_scan2(const int* __restrict__ bsum, int* __restrict__ bpre,
                        int* __restrict__ offs) {
    __shared__ int sm[256];
    int tid = threadIdx.x;
    int v = (tid < NB) ? bsum[tid] : 0;
    sm[tid] = v;
    __syncthreads();
    for (int off = 1; off < 256; off <<= 1) {
        int t = (tid >= off) ? sm[tid - off] : 0;
        __syncthreads();
        sm[tid] += t;
        __syncthreads();
    }
    if (tid < NB) bpre[tid] = sm[tid] - v;
    if (tid == 255) offs[NN] = sm[255];
}

__global__ void k_scan3(int* __restrict__ offs, const int* __restrict__ bpre,
                        int* __restrict__ cursor) {
    int i = blockIdx.x * 256 + threadIdx.x;
    if (i < NN) {
        int v = offs[i] + bpre[blockIdx.x];
        offs[i] = v;
        cursor[i] = v;
    }
}

// ---- mean aggregation from bf16 table [NN][128] -> bf16 mean plane [NN][128] ----
// one wave per node; 16-lane subwave per edge (16B/lane); fully predicated 4-deep gather.
__global__ __launch_bounds__(256) void k_aggb(
    const short* __restrict__ hb, const int* __restrict__ offs,
    const int* __restrict__ ssrc, short* __restrict__ mH) {
    int wid = (blockIdx.x * 256 + threadIdx.x) >> 6;
    int lane = threadIdx.x & 63;
    if (wid >= NN) return;
    int sub = lane >> 4, l16 = lane & 15;
    int beg = offs[wid], end = offs[wid + 1];
    f32x4 a0 = {0.f, 0.f, 0.f, 0.f}, a1 = {0.f, 0.f, 0.f, 0.f};
    for (int i = beg + sub; i < end; i += 16) {
        int i1 = i + 4, i2 = i + 8, i3 = i + 12;
        int em1 = end - 1;
        int s0 = ssrc[i];
        int s1 = ssrc[min(i1, em1)];
        int s2 = ssrc[min(i2, em1)];
        int s3 = ssrc[min(i3, em1)];
        float w1 = (i1 < end) ? 1.f : 0.f;
        float w2 = (i2 < end) ? 1.f : 0.f;
        float w3 = (i3 < end) ? 1.f : 0.f;
        short8 v0 = *(const short8*)(hb + (size_t)s0 * 128 + l16 * 8);
        short8 v1 = *(const short8*)(hb + (size_t)s1 * 128 + l16 * 8);
        short8 v2 = *(const short8*)(hb + (size_t)s2 * 128 + l16 * 8);
        short8 v3 = *(const short8*)(hb + (size_t)s3 * 128 + l16 * 8);
#pragma unroll
        for (int j = 0; j < 4; ++j) {
            a0[j] += (bf2f((unsigned short)v0[j]) + w1 * bf2f((unsigned short)v1[j])) +
                     (w2 * bf2f((unsigned short)v2[j]) + w3 * bf2f((unsigned short)v3[j]));
            a1[j] += (bf2f((unsigned short)v0[j + 4]) + w1 * bf2f((unsigned short)v1[j + 4])) +
                     (w2 * bf2f((unsigned short)v2[j + 4]) + w3 * bf2f((unsigned short)v3[j + 4]));
        }
    }
#pragma unroll
    for (int j = 0; j < 4; ++j) {
        a0[j] += __shfl_xor(a0[j], 16);
        a0[j] += __shfl_xor(a0[j], 32);
        a1[j] += __shfl_xor(a1[j], 16);
        a1[j] += __shfl_xor(a1[j], 32);
    }
    if (sub == 0) {
        float inv = 1.f / fmaxf((float)(end - beg), 1.f);
        a0 *= inv; a1 *= inv;
        short8 hv;
#pragma unroll
        for (int j = 0; j < 4; ++j) {
            hv[j] = (short)f2bf(a0[j]);
            hv[j + 4] = (short)f2bf(a1[j]);
        }
        *(short8*)(mH + (size_t)wid * 128 + l16 * 8) = hv;
    }
}

// ---------------- MFMA GEMM body: counted-vmcnt pipeline, race-free ordering ----------------
// 512 threads = 8 waves; wave w owns rows [bx*128 + w*16, +16) x BN cols.
// Per iteration ck: wait vmcnt(NA) -> s_barrier -> stage(ck+1) -> cvtA/ldA(ck+2) -> compute(ck).
template <int BN, int KPAD, int KS0, int KREAL, bool AFP32, bool RELU, bool PQ>
__device__ __forceinline__ void gemm_body(
    const void* __restrict__ A0v, const short* __restrict__ A1,
    const short* __restrict__ Bg, const float* __restrict__ bias,
    short* __restrict__ CH, int ldc,
    float* __restrict__ F0, float* __restrict__ F1, int splitN,
    int M, int N, int bx, int by) {
    constexpr int NT = BN / 16;          // col tiles per wave
    constexpr int C = KPAD / 64;         // 64-wide k-chunks
    constexpr int PT = (BN * 16) / 512;  // gload_lds issues per thread per chunk
    constexpr int SLAB = BN * 128;       // shorts per buffer
    constexpr int NA = AFP32 ? 4 : 0;    // A global loads per thread per chunk
    static_assert((BN * 16) % 512 == 0, "staging divisibility");
    static_assert(C >= 3, "peel structure needs >=3 chunks");
    __shared__ short Bs[2 * SLAB];
    int tid = threadIdx.x;
    int wave = tid >> 6, lane = tid & 63;
    int quad = lane >> 4, l16 = lane & 15;
    int colBase = by * BN;
    int r0 = bx * 128 + wave * 16 + l16;
    int r0c = min(r0, M - 1);
    const short* Bbase = Bg + (size_t)by * (C * SLAB);

    f32x4 acc[NT];
#pragma unroll
    for (int n = 0; n < NT; ++n) acc[n] = (f32x4){0.f, 0.f, 0.f, 0.f};

    auto stageB = [&](int buf, int ck) {
        const short* src = Bbase + (size_t)ck * SLAB;
        short* db = Bs + buf * SLAB;
#pragma unroll
        for (int u = 0; u < PT; ++u) {
            int base = u * 512 + wave * 64;                 // wave-uniform chunk base
            gl16(src + (size_t)(base + lane) * 8, db + (size_t)base * 8);
        }
    };

    short8 aPre[AFP32 ? 2 : (2 * C)];
    short8 aCur[2];
    f32x4 fN[2][4];   // fp32 A double-buffer (2 chunks in flight)
    const float* Af = (const float*)A0v + (size_t)r0c * (size_t)KREAL;

    auto ldA32 = [&](int slot, int ck) {
#pragma unroll
        for (int s = 0; s < 2; ++s) {
            int kg = ck * 64 + s * 32 + quad * 8;
            f32x4 f0 = {0.f, 0.f, 0.f, 0.f}, f1 = {0.f, 0.f, 0.f, 0.f};
            if (kg < KREAL) f0 = *(const f32x4*)(Af + kg);
            if (kg + 4 < KREAL) f1 = *(const f32x4*)(Af + kg + 4);
            fN[slot][s * 2] = f0;
            fN[slot][s * 2 + 1] = f1;
        }
    };
    auto cvtA = [&](int slot) {
#pragma unroll
        for (int s = 0; s < 2; ++s) {
            short8 a;
#pragma unroll
            for (int j = 0; j < 4; ++j) {
                a[j] = (short)f2bf(fN[slot][s * 2][j]);
                a[j + 4] = (short)f2bf(fN[slot][s * 2 + 1][j]);
            }
            aCur[s] = a;
        }
    };
    auto compute = [&](int ck) {
        const short* bb = Bs + (ck & 1) * SLAB;
#pragma unroll
        for (int s = 0; s < 2; ++s) {
            short8 a;
            if constexpr (AFP32) a = aCur[s];
            else                 a = aPre[ck * 2 + s];
#pragma unroll
            for (int n = 0; n < NT; ++n) {
                int r = n * 16 + l16;
                int ch = (s * 4 + quad) ^ (r & 7);
                short8 bh = *(const short8*)(bb + r * 128 + ch * 8);
                short8 bl = *(const short8*)(bb + r * 128 + (8 + ch) * 8);
                acc[n] = __builtin_amdgcn_mfma_f32_16x16x32_bf16(a, bh, acc[n], 0, 0, 0);
                acc[n] = __builtin_amdgcn_mfma_f32_16x16x32_bf16(a, bl, acc[n], 0, 0, 0);
            }
        }
    };

    // ---- prologue: stage(0) first, then A(0), A(1) (so vmcnt(NA) covers stage0+A0) ----
    if constexpr (!AFP32) {
        const short* A0 = (const short*)A0v;
#pragma unroll
        for (int c = 0; c < C; ++c) {
            const bool seg = (c * 64 >= KS0);
            const short* ap = seg ? A1 : A0;
            const int w = seg ? (KPAD - KS0) : KS0;
            const int col = c * 64 - (seg ? KS0 : 0);
#pragma unroll
            for (int s = 0; s < 2; ++s)
                aPre[c * 2 + s] =
                    *(const short8*)(ap + (size_t)r0c * w + col + s * 32 + quad * 8);
        }
    }
    stageB(0, 0);
    if constexpr (AFP32) { ldA32(0, 0); ldA32(1, 1); }

    // ---- main loop: wait(own stage ck) -> barrier -> stage(ck+1) -> compute(ck) ----
#pragma unroll
    for (int ck = 0; ck <= C - 2; ++ck) {
        asm volatile("s_waitcnt vmcnt(%0)" ::"n"(NA) : "memory");
        __builtin_amdgcn_s_barrier();
        __builtin_amdgcn_sched_barrier(0);
        stageB((ck + 1) & 1, ck + 1);
        if constexpr (AFP32) {
            cvtA(ck & 1);
            if (ck + 2 < C) ldA32(ck & 1, ck + 2);
        }
        compute(ck);
    }
    {   // ck = C-1: nothing issued after stage(C-1) -> full drain (only one in the loop)
        asm volatile("s_waitcnt vmcnt(0)" ::: "memory");
        __builtin_amdgcn_s_barrier();
        __builtin_amdgcn_sched_barrier(0);
        if constexpr (AFP32) cvtA((C - 1) & 1);
        compute(C - 1);
    }

    // ---- epilogue: C-layout col=lane&15, row=quad*4+reg ----
    int gr0 = bx * 128 + wave * 16 + quad * 4;
#pragma unroll
    for (int n = 0; n < NT; ++n) {
        int gc = colBase + n * 16 + l16;
        if (gc >= N) continue;
        float b = bias ? bias[gc] : 0.f;
#pragma unroll
        for (int r = 0; r < 4; ++r) {
            int gr = gr0 + r;
            if (gr < M) {
                float v = acc[n][r] + b;
                if (RELU) v = fmaxf(v, 0.f);
                if constexpr (PQ) {
                    if (gc < splitN) CH[(size_t)gr * ldc + gc] = (short)f2bf(v);
                    else             F0[(size_t)gr * (N - splitN) + (gc - splitN)] = v;
                } else {
                    if (CH) CH[(size_t)gr * ldc + gc] = (short)f2bf(v);
                    if (F0) {
                        if (gc < splitN) F0[(size_t)gr * splitN + gc] = v;
                        else             F1[(size_t)gr * (N - splitN) + (gc - splitN)] = v;
                    }
                }
            }
        }
    }
}

template <int BN, int KPAD, int KS0, int KREAL, bool AFP32, bool RELU, bool PQ>
__global__ __launch_bounds__(512, 4) void k_mm8(
    const void* __restrict__ A0v, const short* __restrict__ A1,
    const short* __restrict__ Bg, const float* __restrict__ bias,
    short* __restrict__ CH, int ldc,
    float* __restrict__ F0, float* __restrict__ F1, int splitN,
    int M, int N) {
    gemm_body<BN, KPAD, KS0, KREAL, AFP32, RELU, PQ>(
        A0v, A1, Bg, bias, CH, ldc, F0, F1, splitN, M, N, blockIdx.x, blockIdx.y);
}

// ---- mega2: GEMM0 (blocks 0..G0-1) + edge scatter (blocks G0..) in one dispatch ----
// Scatter rides in GEMM0's idle wave slots (GEMM0 latency-bound, 1.16 TB/s, 8% MFMA).
__global__ __launch_bounds__(512, 4) void k_mega2(
    const float* __restrict__ x, const short* __restrict__ m_w,
    const float* __restrict__ b_map, short* __restrict__ h0H,
    const int* __restrict__ esrc, const int* __restrict__ edst,
    int* __restrict__ cursor, int* __restrict__ ssrc) {
    if (blockIdx.x < G0) {
        gemm_body<128, 512, 512, FIN, true, false, false>(
            (const void*)x, nullptr, m_w, b_map,
            h0H, 128, nullptr, nullptr, 0, NN, 128, blockIdx.x, 0);
    } else {
        int e = (blockIdx.x - G0) * 512 + threadIdx.x;
        if (e < NE) {
            int p = atomicAdd(&cursor[edst[e]], 1);
            ssrc[p] = esrc[e];
        }
    }
}

// ---------------- fused layer-3 aggregation + bias + residual + log_softmax ----------------
// pH: bf16 [NN][64] (cols 0-39 valid); q: fp32 [NN][40]; predicated 4-deep gather.
__global__ __launch_bounds__(256) void k_final(
    const short* __restrict__ pH, const float* __restrict__ q,
    const int* __restrict__ offs, const int* __restrict__ ssrc,
    const float* __restrict__ bl3, float* __restrict__ out) {
    int wid = (blockIdx.x * 256 + threadIdx.x) >> 6;
    int lane = threadIdx.x & 63;
    if (wid >= NN) return;
    bool act = lane < NCLS;
    int beg = offs[wid], end = offs[wid + 1];
    float a0 = 0.f, a1 = 0.f, a2 = 0.f, a3 = 0.f;
    for (int i = beg; i < end; i += 4) {
        int em1 = end - 1;
        int s0 = ssrc[i];
        int s1 = ssrc[min(i + 1, em1)];
        int s2 = ssrc[min(i + 2, em1)];
        int s3 = ssrc[min(i + 3, em1)];
        float w1 = (i + 1 < end) ? 1.f : 0.f;
        float w2 = (i + 2 < end) ? 1.f : 0.f;
        float w3 = (i + 3 < end) ? 1.f : 0.f;
        if (act) {
            a0 += bf2f((unsigned short)pH[(size_t)s0 * 64 + lane]);
            a1 += w1 * bf2f((unsigned short)pH[(size_t)s1 * 64 + lane]);
            a2 += w2 * bf2f((unsigned short)pH[(size_t)s2 * 64 + lane]);
            a3 += w3 * bf2f((unsigned short)pH[(size_t)s3 * 64 + lane]);
        }
    }
    float inv = 1.f / fmaxf((float)(end - beg), 1.f);
    float v = act ? ((a0 + a1) + (a2 + a3)) * inv + bl3[lane] + q[(size_t)wid * NCLS + lane]
                  : -INFINITY;
    float m = v;
#pragma unroll
    for (int off = 32; off > 0; off >>= 1) m = fmaxf(m, __shfl_xor(m, off));
    float e = act ? expf(v - m) : 0.f;
    float s = e;
#pragma unroll
    for (int off = 32; off > 0; off >>= 1) s += __shfl_xor(s, off);
    float ls = logf(s);
    if (act) out[(size_t)wid * NCLS + lane] = v - m - ls;
}

extern "C" void kernel_launch(void* const* d_in, const int* in_sizes, int n_in,
                              void* d_out, int out_size, void* d_ws, size_t ws_size,
                              hipStream_t stream) {
    const float* x    = (const float*)d_in[0];
    const int*   ei   = (const int*)d_in[1];
    const int*   esrc = ei;        // row 0: src
    const int*   edst = ei + NE;   // row 1: dst
    const float* W_map = (const float*)d_in[2];
    const float* b_map = (const float*)d_in[3];
    const float* Wl1   = (const float*)d_in[4];
    const float* bl1   = (const float*)d_in[5];
    const float* Wr1   = (const float*)d_in[6];
    const float* Wl2   = (const float*)d_in[7];
    const float* bl2   = (const float*)d_in[8];
    const float* Wr2   = (const float*)d_in[9];
    const float* Wl3   = (const float*)d_in[10];
    const float* bl3   = (const float*)d_in[11];
    const float* Wr3   = (const float*)d_in[12];
    float* out = (float*)d_out;

    char* ws = (char*)d_ws;
    short* h0H = (short*)ws; ws += (size_t)NN * 128 * 2;
    short* m0H = (short*)ws; ws += (size_t)NN * 128 * 2;
    short* h1H = (short*)ws; ws += (size_t)NN * 128 * 2;
    short* m1H = (short*)ws; ws += (size_t)NN * 128 * 2;
    short* h2H = (short*)ws; ws += (size_t)NN * 256 * 2;
    short* pH  = (short*)ws; ws += (size_t)NN * 64 * 2;   // bf16, rows padded to 64
    float* q   = (float*)ws; ws += (size_t)NN * NCLS * 4;
    short* wt  = (short*)ws; ws += (size_t)376832 * 2;
    int* deg    = (int*)ws;  ws += (size_t)NN * 4;
    int* offs   = (int*)ws;  ws += (size_t)(NN + 2) * 4;
    int* cursor = (int*)ws;  ws += (size_t)NN * 4;
    int* ssrc   = (int*)ws;  ws += (size_t)NE * 4;
    int* bsum   = (int*)ws;  ws += (size_t)256 * 4;
    int* bpre   = (int*)ws;  ws += (size_t)256 * 4;

    // blocked pre-swizzled weight buffers: [yb][ck64][BN][128], BN=128 (b3w: 96)
    short* m_w  = wt + 0;       // 1yb * 8ck * 128 * 128 = 131072
    short* b1w  = wt + 131072;  // 1yb * 4ck * 128 * 128 = 65536
    short* b2w  = wt + 196608;  // 2yb * 4ck * 128 * 128 = 131072
    short* b3w  = wt + 327680;  // 1yb * 4ck *  96 * 128 = 49152  (total 376832)

    const int g128 = (NN + 127) / 128;  // 391 == G0
    const int aggBlocks = (NN * 64) / 256;
    const int wsb = (WSE + 511) / 512;  // 376

    // --- mega1: degree count + all weight splits (+b3w pad zero) in one dispatch ---
    (void)hipMemsetAsync(deg, 0, (size_t)NN * 4, stream);
    k_mega1<<<CNTB + wsb, 512, 0, stream>>>(edst, deg, W_map, Wr1, Wl1, Wr2, Wl2,
                                            Wl3, Wr3, m_w, b1w, b2w, b3w);

    // --- two-level scan of degrees ---
    k_scan1<<<NB, 256, 0, stream>>>(deg, offs, bsum);
    k_scan2<<<1, 256, 0, stream>>>(bsum, bpre, offs);
    k_scan3<<<NB, 256, 0, stream>>>(offs, bpre, cursor);

    // --- mega2: GEMM0 (h0 = x@W_map + b_map -> h0H) + edge scatter, one dispatch ---
    k_mega2<<<G0 + CNTB, 512, 0, stream>>>(x, m_w, b_map, h0H, esrc, edst, cursor, ssrc);

    // mean(h0) -> m0H
    k_aggb<<<aggBlocks, 256, 0, stream>>>(h0H, offs, ssrc, m0H);

    // h1 = relu([h0|mean] @ [Wr1;Wl1] + bl1) -> h1H
    k_mm8<128, 256, 128, 256, false, true, false><<<dim3(g128, 1), 512, 0, stream>>>(
        (const void*)h0H, m0H, b1w, bl1,
        h1H, 128, nullptr, nullptr, 0, NN, 128);

    // mean(h1) -> m1H
    k_aggb<<<aggBlocks, 256, 0, stream>>>(h1H, offs, ssrc, m1H);

    // h2 = relu([h1|mean] @ [Wr2;Wl2] + bl2) -> h2H [NN][256]
    k_mm8<128, 256, 128, 256, false, true, false><<<dim3(g128, 2), 512, 0, stream>>>(
        (const void*)h1H, m1H, b2w, bl2,
        h2H, 256, nullptr, nullptr, 0, NN, 256);

    // [p|q] = h2 @ [Wl3|Wr3] (BN padded to 96): cols 0-39 -> pH (bf16, ldc=64), 40-79 -> q
    k_mm8<96, 256, 256, 256, false, false, true><<<dim3(g128, 1), 512, 0, stream>>>(
        (const void*)h2H, nullptr, b3w, nullptr,
        pH, 64, q, nullptr, NCLS, NN, 80);

    // fused: logits = mean_agg(pH) + bl3 + q; log_softmax -> out
    k_final<<<aggBlocks, 256, 0, stream>>>(pH, q, offs, ssrc, bl3, out);
}

// Round 13
// 397.322 us; speedup vs baseline: 1.2365x; 1.0398x over previous
//
#include <hip/hip_runtime.h>
#include <math.h>

#define NN 50000
#define NE 800000
#define FIN 500
#define NCLS 40
#define NB 196   // scan blocks = ceil(NN/256)
#define G0 391   // GEMM row blocks = ceil(NN/128)
#define CNTB 1563 // count/scatter blocks = ceil(NE/512)
#define WSE 192512 // fused wsplit total elements

typedef short short8 __attribute__((ext_vector_type(8)));
typedef float f32x4 __attribute__((ext_vector_type(4)));

__device__ __forceinline__ unsigned short f2bf(float f) {
    unsigned u = __float_as_uint(f);
    unsigned r = (u + 0x7FFFu + ((u >> 16) & 1u)) >> 16;
    return (unsigned short)r;
}
__device__ __forceinline__ float bf2f(unsigned short h) {
    return __uint_as_float(((unsigned)h) << 16);
}

// global -> LDS direct copy, 16B per lane; LDS dest is wave-uniform base + lane*16
typedef const __attribute__((address_space(1))) void gv1;
typedef __attribute__((address_space(3))) void lv3;
__device__ __forceinline__ void gl16(const void* g, void* l) {
    __builtin_amdgcn_global_load_lds((gv1*)g, (lv3*)l, 16, 0, 0);
}

// ---- weight split+transpose into blocked, pre-swizzled layout ----
// dst layout: [yb][ck64][r (0..BN-1)][16 x 16B-chunks: hi 0-7, lo 8-15, chunk^ (r&7)]
__device__ __forceinline__ void wsplit_one(
    const float* __restrict__ W, short* __restrict__ dst,
    int Ksrc, int Ncols, int Kpad, int BN, int koff, int noff, int llog, int i) {
    int n = i >> llog, kk = i & ((1 << llog) - 1);
    float v = (kk < Ksrc) ? W[(size_t)kk * Ncols + n] : 0.f;
    unsigned short hi = f2bf(v);
    float lo = v - bf2f(hi);
    int nd = noff + n, kd = koff + kk;
    int yb = nd / BN, r = nd % BN;
    int ck = kd >> 6, kin = kd & 63;
    int c16h = (kin >> 3) ^ (r & 7);
    size_t rowb = (((size_t)yb * (Kpad >> 6) + ck) * BN + r) * 128;
    dst[rowb + c16h * 8 + (kin & 7)] = (short)hi;
    dst[rowb + (8 + c16h) * 8 + (kin & 7)] = (short)f2bf(lo);
}

// ---- mega1: edge-degree count (atomics) + all weight splits + b3w pad zero ----
__global__ __launch_bounds__(512) void k_mega1(
    const int* __restrict__ edst, int* __restrict__ deg,
    const float* __restrict__ W_map,
    const float* __restrict__ Wr1, const float* __restrict__ Wl1,
    const float* __restrict__ Wr2, const float* __restrict__ Wl2,
    const float* __restrict__ Wl3, const float* __restrict__ Wr3,
    short* __restrict__ m_w, short* __restrict__ b1w,
    short* __restrict__ b2w, short* __restrict__ b3w) {
    int tid = threadIdx.x;
    if (blockIdx.x < CNTB) {
        int e = blockIdx.x * 512 + tid;
        if (e < NE) atomicAdd(&deg[edst[e]], 1);
        return;
    }
    int idx = (blockIdx.x - CNTB) * 512 + tid;
    if (idx < 65536)       wsplit_one(W_map, m_w, FIN, 128, 512, 128, 0, 0, 9, idx);
    else if (idx < 81920)  wsplit_one(Wr1, b1w, 128, 128, 256, 128, 0, 0, 7, idx - 65536);
    else if (idx < 98304)  wsplit_one(Wl1, b1w, 128, 128, 256, 128, 128, 0, 7, idx - 81920);
    else if (idx < 131072) wsplit_one(Wr2, b2w, 128, 256, 256, 128, 0, 0, 7, idx - 98304);
    else if (idx < 163840) wsplit_one(Wl2, b2w, 128, 256, 256, 128, 128, 0, 7, idx - 131072);
    else if (idx < 174080) wsplit_one(Wl3, b3w, 256, 40, 256, 96, 0, 0, 8, idx - 163840);
    else if (idx < 184320) wsplit_one(Wr3, b3w, 256, 40, 256, 96, 0, 40, 8, idx - 174080);
    else if (idx < WSE) {  // zero b3w pad rows 80-95 (all 4 ck)
        int j = idx - 184320;
        int ck = j >> 11, rem = j & 2047;
        int r = 80 + (rem >> 7), c = rem & 127;
        b3w[((size_t)(ck * 96 + r)) * 128 + c] = 0;
    }
}

// ---------------- two-level scan of degrees ----------------
__global__ void k_scan1(const int* __restrict__ deg, int* __restrict__ offs,
                        int* __restrict__ bsum) {
    __shared__ int sm[256];
    int tid = threadIdx.x;
    int i = blockIdx.x * 256 + tid;
    int v = (i < NN) ? deg[i] : 0;
    sm[tid] = v;
    __syncthreads();
    for (int off = 1; off < 256; off <<= 1) {
        int t = (tid >= off) ? sm[tid - off] : 0;
        __syncthreads();
        sm[tid] += t;
        __syncthreads();
    }
    if (i < NN) offs[i] = sm[tid] - v;
    if (tid == 255) bsum[blockIdx.x] = sm[255];
}

__global__ void k_scan2(const int* __restrict__ bsum, int* __restrict__ bpre,
                        int* __restrict__ offs) {
    __shared__ int sm[256];
    int tid = threadIdx.x;
    int v = (tid < NB) ? bsum[tid] : 0;
    sm[tid] = v;
    __syncthreads();
    for (int off = 1; off < 256; off <<= 1) {
        int t = (tid >= off) ? sm[tid - off] : 0;
        __syncthreads();
        sm[tid] += t;
        __syncthreads();
    }
    if (tid < NB) bpre[tid] = sm[tid] - v;
    if (tid == 255) offs[NN] = sm[255];
}

__global__ void k_scan3(int* __restrict__ offs, const int* __restrict__ bpre,
                        int* __restrict__ cursor) {
    int i = blockIdx.x * 256 + threadIdx.x;
    if (i < NN) {
        int v = offs[i] + bpre[blockIdx.x];
        offs[i] = v;
        cursor[i] = v;
    }
}

// ---- mean aggregation from bf16 table [NN][128] -> bf16 mean plane [NN][128] ----
// one wave per node; 16-lane subwave per edge (16B/lane); fully predicated 4-deep gather.
__global__ __launch_bounds__(256) void k_aggb(
    const short* __restrict__ hb, const int* __restrict__ offs,
    const int* __restrict__ ssrc, short* __restrict__ mH) {
    int wid = (blockIdx.x * 256 + threadIdx.x) >> 6;
    int lane = threadIdx.x & 63;
    if (wid >= NN) return;
    int sub = lane >> 4, l16 = lane & 15;
    int beg = offs[wid], end = offs[wid + 1];
    f32x4 a0 = {0.f, 0.f, 0.f, 0.f}, a1 = {0.f, 0.f, 0.f, 0.f};
    for (int i = beg + sub; i < end; i += 16) {
        int i1 = i + 4, i2 = i + 8, i3 = i + 12;
        int em1 = end - 1;
        int s0 = ssrc[i];
        int s1 = ssrc[min(i1, em1)];
        int s2 = ssrc[min(i2, em1)];
        int s3 = ssrc[min(i3, em1)];
        float w1 = (i1 < end) ? 1.f : 0.f;
        float w2 = (i2 < end) ? 1.f : 0.f;
        float w3 = (i3 < end) ? 1.f : 0.f;
        short8 v0 = *(const short8*)(hb + (size_t)s0 * 128 + l16 * 8);
        short8 v1 = *(const short8*)(hb + (size_t)s1 * 128 + l16 * 8);
        short8 v2 = *(const short8*)(hb + (size_t)s2 * 128 + l16 * 8);
        short8 v3 = *(const short8*)(hb + (size_t)s3 * 128 + l16 * 8);
#pragma unroll
        for (int j = 0; j < 4; ++j) {
            a0[j] += (bf2f((unsigned short)v0[j]) + w1 * bf2f((unsigned short)v1[j])) +
                     (w2 * bf2f((unsigned short)v2[j]) + w3 * bf2f((unsigned short)v3[j]));
            a1[j] += (bf2f((unsigned short)v0[j + 4]) + w1 * bf2f((unsigned short)v1[j + 4])) +
                     (w2 * bf2f((unsigned short)v2[j + 4]) + w3 * bf2f((unsigned short)v3[j + 4]));
        }
    }
#pragma unroll
    for (int j = 0; j < 4; ++j) {
        a0[j] += __shfl_xor(a0[j], 16);
        a0[j] += __shfl_xor(a0[j], 32);
        a1[j] += __shfl_xor(a1[j], 16);
        a1[j] += __shfl_xor(a1[j], 32);
    }
    if (sub == 0) {
        float inv = 1.f / fmaxf((float)(end - beg), 1.f);
        a0 *= inv; a1 *= inv;
        short8 hv;
#pragma unroll
        for (int j = 0; j < 4; ++j) {
            hv[j] = (short)f2bf(a0[j]);
            hv[j + 4] = (short)f2bf(a1[j]);
        }
        *(short8*)(mH + (size_t)wid * 128 + l16 * 8) = hv;
    }
}

// ---------------- MFMA GEMM body: counted-vmcnt pipeline, race-free ordering ----------------
template <int BN, int KPAD, int KS0, int KREAL, bool AFP32, bool RELU, bool PQ>
__device__ __forceinline__ void gemm_body(
    const void* __restrict__ A0v, const short* __restrict__ A1,
    const short* __restrict__ Bg, const float* __restrict__ bias,
    short* __restrict__ CH, int ldc,
    float* __restrict__ F0, float* __restrict__ F1, int splitN,
    int M, int N, int bx, int by) {
    constexpr int NT = BN / 16;
    constexpr int C = KPAD / 64;
    constexpr int PT = (BN * 16) / 512;
    constexpr int SLAB = BN * 128;
    constexpr int NA = AFP32 ? 4 : 0;
    static_assert((BN * 16) % 512 == 0, "staging divisibility");
    static_assert(C >= 3, "peel structure needs >=3 chunks");
    __shared__ short Bs[2 * SLAB];
    int tid = threadIdx.x;
    int wave = tid >> 6, lane = tid & 63;
    int quad = lane >> 4, l16 = lane & 15;
    int colBase = by * BN;
    int r0 = bx * 128 + wave * 16 + l16;
    int r0c = min(r0, M - 1);
    const short* Bbase = Bg + (size_t)by * (C * SLAB);

    f32x4 acc[NT];
#pragma unroll
    for (int n = 0; n < NT; ++n) acc[n] = (f32x4){0.f, 0.f, 0.f, 0.f};

    auto stageB = [&](int buf, int ck) {
        const short* src = Bbase + (size_t)ck * SLAB;
        short* db = Bs + buf * SLAB;
#pragma unroll
        for (int u = 0; u < PT; ++u) {
            int base = u * 512 + wave * 64;
            gl16(src + (size_t)(base + lane) * 8, db + (size_t)base * 8);
        }
    };

    short8 aPre[AFP32 ? 2 : (2 * C)];
    short8 aCur[2];
    f32x4 fN[2][4];
    const float* Af = (const float*)A0v + (size_t)r0c * (size_t)KREAL;

    auto ldA32 = [&](int slot, int ck) {
#pragma unroll
        for (int s = 0; s < 2; ++s) {
            int kg = ck * 64 + s * 32 + quad * 8;
            f32x4 f0 = {0.f, 0.f, 0.f, 0.f}, f1 = {0.f, 0.f, 0.f, 0.f};
            if (kg < KREAL) f0 = *(const f32x4*)(Af + kg);
            if (kg + 4 < KREAL) f1 = *(const f32x4*)(Af + kg + 4);
            fN[slot][s * 2] = f0;
            fN[slot][s * 2 + 1] = f1;
        }
    };
    auto cvtA = [&](int slot) {
#pragma unroll
        for (int s = 0; s < 2; ++s) {
            short8 a;
#pragma unroll
            for (int j = 0; j < 4; ++j) {
                a[j] = (short)f2bf(fN[slot][s * 2][j]);
                a[j + 4] = (short)f2bf(fN[slot][s * 2 + 1][j]);
            }
            aCur[s] = a;
        }
    };
    auto compute = [&](int ck) {
        const short* bb = Bs + (ck & 1) * SLAB;
#pragma unroll
        for (int s = 0; s < 2; ++s) {
            short8 a;
            if constexpr (AFP32) a = aCur[s];
            else                 a = aPre[ck * 2 + s];
#pragma unroll
            for (int n = 0; n < NT; ++n) {
                int r = n * 16 + l16;
                int ch = (s * 4 + quad) ^ (r & 7);
                short8 bh = *(const short8*)(bb + r * 128 + ch * 8);
                short8 bl = *(const short8*)(bb + r * 128 + (8 + ch) * 8);
                acc[n] = __builtin_amdgcn_mfma_f32_16x16x32_bf16(a, bh, acc[n], 0, 0, 0);
                acc[n] = __builtin_amdgcn_mfma_f32_16x16x32_bf16(a, bl, acc[n], 0, 0, 0);
            }
        }
    };

    if constexpr (!AFP32) {
        const short* A0 = (const short*)A0v;
#pragma unroll
        for (int c = 0; c < C; ++c) {
            const bool seg = (c * 64 >= KS0);
            const short* ap = seg ? A1 : A0;
            const int w = seg ? (KPAD - KS0) : KS0;
            const int col = c * 64 - (seg ? KS0 : 0);
#pragma unroll
            for (int s = 0; s < 2; ++s)
                aPre[c * 2 + s] =
                    *(const short8*)(ap + (size_t)r0c * w + col + s * 32 + quad * 8);
        }
    }
    stageB(0, 0);
    if constexpr (AFP32) { ldA32(0, 0); ldA32(1, 1); }

#pragma unroll
    for (int ck = 0; ck <= C - 2; ++ck) {
        asm volatile("s_waitcnt vmcnt(%0)" ::"n"(NA) : "memory");
        __builtin_amdgcn_s_barrier();
        __builtin_amdgcn_sched_barrier(0);
        stageB((ck + 1) & 1, ck + 1);
        if constexpr (AFP32) {
            cvtA(ck & 1);
            if (ck + 2 < C) ldA32(ck & 1, ck + 2);
        }
        compute(ck);
    }
    {
        asm volatile("s_waitcnt vmcnt(0)" ::: "memory");
        __builtin_amdgcn_s_barrier();
        __builtin_amdgcn_sched_barrier(0);
        if constexpr (AFP32) cvtA((C - 1) & 1);
        compute(C - 1);
    }

    int gr0 = bx * 128 + wave * 16 + quad * 4;
#pragma unroll
    for (int n = 0; n < NT; ++n) {
        int gc = colBase + n * 16 + l16;
        if (gc >= N) continue;
        float b = bias ? bias[gc] : 0.f;
#pragma unroll
        for (int r = 0; r < 4; ++r) {
            int gr = gr0 + r;
            if (gr < M) {
                float v = acc[n][r] + b;
                if (RELU) v = fmaxf(v, 0.f);
                if constexpr (PQ) {
                    if (gc < splitN) CH[(size_t)gr * ldc + gc] = (short)f2bf(v);
                    else             F0[(size_t)gr * (N - splitN) + (gc - splitN)] = v;
                } else {
                    if (CH) CH[(size_t)gr * ldc + gc] = (short)f2bf(v);
                    if (F0) {
                        if (gc < splitN) F0[(size_t)gr * splitN + gc] = v;
                        else             F1[(size_t)gr * (N - splitN) + (gc - splitN)] = v;
                    }
                }
            }
        }
    }
}

template <int BN, int KPAD, int KS0, int KREAL, bool AFP32, bool RELU, bool PQ>
__global__ __launch_bounds__(512, 4) void k_mm8(
    const void* __restrict__ A0v, const short* __restrict__ A1,
    const short* __restrict__ Bg, const float* __restrict__ bias,
    short* __restrict__ CH, int ldc,
    float* __restrict__ F0, float* __restrict__ F1, int splitN,
    int M, int N) {
    gemm_body<BN, KPAD, KS0, KREAL, AFP32, RELU, PQ>(
        A0v, A1, Bg, bias, CH, ldc, F0, F1, splitN, M, N, blockIdx.x, blockIdx.y);
}

// ---- mega2: GEMM0 (blocks 0..G0-1) + edge scatter (blocks G0..) in one dispatch ----
__global__ __launch_bounds__(512, 4) void k_mega2(
    const float* __restrict__ x, const short* __restrict__ m_w,
    const float* __restrict__ b_map, short* __restrict__ h0H,
    const int* __restrict__ esrc, const int* __restrict__ edst,
    int* __restrict__ cursor, int* __restrict__ ssrc) {
    if (blockIdx.x < G0) {
        gemm_body<128, 512, 512, FIN, true, false, false>(
            (const void*)x, nullptr, m_w, b_map,
            h0H, 128, nullptr, nullptr, 0, NN, 128, blockIdx.x, 0);
    } else {
        int e = (blockIdx.x - G0) * 512 + threadIdx.x;
        if (e < NE) {
            int p = atomicAdd(&cursor[edst[e]], 1);
            ssrc[p] = esrc[e];
        }
    }
}

// ---- fused mm2+mm3: h2 both halves -> LDS tile H, then [p|q] = H @ W3 ----
// One block = 128 rows. A=[h1|m1] fragments loaded ONCE (both y passes).
// Per y pass: stage B2[y] (counted-vmcnt loop), MFMA, epilogue relu+bf16 into
// H[128][256] LDS (16B-chunk XOR (row&7) swizzle -> 2-way on mm3 ds_read_b128).
// Then mm3 K-loop: A-fragments from H (LDS), B3 staged into freed Bs buffers.
// h2 never touches global: saves 51MB HBM round-trip + 1 dispatch. Numerics
// identical (same bf16 values, same MFMA order).
__global__ __launch_bounds__(512, 2) void k_mm23(
    const short* __restrict__ h1H, const short* __restrict__ m1H,
    const short* __restrict__ b2w, const float* __restrict__ bl2,
    const short* __restrict__ b3w, short* __restrict__ pH,
    float* __restrict__ q) {
    constexpr int SLAB2 = 128 * 128;  // 16384 shorts = 32KB
    constexpr int SLAB3 = 96 * 128;   // 12288 shorts = 24KB
    __shared__ short Bs[2 * SLAB2];   // 64KB (reused for B3 dbuf in mm3 phase)
    __shared__ short H[128 * 256];    // 64KB h2 tile
    int tid = threadIdx.x;
    int wave = tid >> 6, lane = tid & 63;
    int quad = lane >> 4, l16 = lane & 15;
    int bx = blockIdx.x;
    int r0 = bx * 128 + wave * 16 + l16;
    int r0c = min(r0, NN - 1);

    // A = [h1 | m1] fragments, loaded once, reused for both y passes
    short8 aPre[8];
#pragma unroll
    for (int c = 0; c < 4; ++c) {
        const short* ap = (c >= 2) ? m1H : h1H;
        int col = (c & 1) * 64;
#pragma unroll
        for (int s = 0; s < 2; ++s)
            aPre[c * 2 + s] =
                *(const short8*)(ap + (size_t)r0c * 128 + col + s * 32 + quad * 8);
    }

    f32x4 acc[8];
    auto compute2 = [&](int ck) {
        const short* bb = Bs + (ck & 1) * SLAB2;
#pragma unroll
        for (int s = 0; s < 2; ++s) {
            short8 a = aPre[ck * 2 + s];
#pragma unroll
            for (int n = 0; n < 8; ++n) {
                int r = n * 16 + l16;
                int ch = (s * 4 + quad) ^ (r & 7);
                short8 bh = *(const short8*)(bb + r * 128 + ch * 8);
                short8 bl = *(const short8*)(bb + r * 128 + (8 + ch) * 8);
                acc[n] = __builtin_amdgcn_mfma_f32_16x16x32_bf16(a, bh, acc[n], 0, 0, 0);
                acc[n] = __builtin_amdgcn_mfma_f32_16x16x32_bf16(a, bl, acc[n], 0, 0, 0);
            }
        }
    };

#pragma unroll
    for (int y = 0; y < 2; ++y) {
        const short* Bbase = b2w + (size_t)y * (4 * SLAB2);
        auto stageB2 = [&](int buf, int ck) {
            const short* src = Bbase + (size_t)ck * SLAB2;
            short* db = Bs + buf * SLAB2;
#pragma unroll
            for (int u = 0; u < 4; ++u) {
                int base = u * 512 + wave * 64;
                gl16(src + (size_t)(base + lane) * 8, db + (size_t)base * 8);
            }
        };
#pragma unroll
        for (int n = 0; n < 8; ++n) acc[n] = (f32x4){0.f, 0.f, 0.f, 0.f};
        stageB2(0, 0);   // safe: prior readers of buf0 finished before last barrier
#pragma unroll
        for (int ck = 0; ck <= 2; ++ck) {
            asm volatile("s_waitcnt vmcnt(0)" ::: "memory");
            __builtin_amdgcn_s_barrier();
            __builtin_amdgcn_sched_barrier(0);
            stageB2((ck + 1) & 1, ck + 1);
            compute2(ck);
        }
        asm volatile("s_waitcnt vmcnt(0)" ::: "memory");
        __builtin_amdgcn_s_barrier();
        __builtin_amdgcn_sched_barrier(0);
        compute2(3);
        // epilogue: relu + bf16 into H (chunk XOR (row&7) swizzle); zero pad rows
        int lr0 = wave * 16 + quad * 4;
#pragma unroll
        for (int n = 0; n < 8; ++n) {
            int gcl = y * 128 + n * 16 + l16;      // h2 col 0..255
            float b = bl2[gcl];
#pragma unroll
            for (int r = 0; r < 4; ++r) {
                int lr = lr0 + r;
                int gr = bx * 128 + lr;
                float v = (gr < NN) ? fmaxf(acc[n][r] + b, 0.f) : 0.f;
                int chunk = (gcl >> 3) ^ (lr & 7);
                H[lr * 256 + chunk * 8 + (gcl & 7)] = (short)f2bf(v);
            }
        }
    }
    __syncthreads();   // H fully written & visible; all Bs reads done

    // ---- mm3: [p|q] = H @ [Wl3|Wr3], A from LDS, B3 via Bs dbuf ----
    auto stageB3 = [&](int buf, int ck) {
        const short* src = b3w + (size_t)ck * SLAB3;
        short* db = Bs + buf * SLAB3;
#pragma unroll
        for (int u = 0; u < 3; ++u) {
            int base = u * 512 + wave * 64;
            gl16(src + (size_t)(base + lane) * 8, db + (size_t)base * 8);
        }
    };
    stageB3(0, 0);
    int row3 = wave * 16 + l16;
    short8 aPre3[8];
#pragma unroll
    for (int c = 0; c < 4; ++c)
#pragma unroll
        for (int s = 0; s < 2; ++s) {
            int col = c * 64 + s * 32 + quad * 8;
            int chunk = (col >> 3) ^ (row3 & 7);
            aPre3[c * 2 + s] = *(const short8*)(H + row3 * 256 + chunk * 8);
        }
    f32x4 acc3[6];
#pragma unroll
    for (int n = 0; n < 6; ++n) acc3[n] = (f32x4){0.f, 0.f, 0.f, 0.f};
    auto compute3 = [&](int ck) {
        const short* bb = Bs + (ck & 1) * SLAB3;
#pragma unroll
        for (int s = 0; s < 2; ++s) {
            short8 a = aPre3[ck * 2 + s];
#pragma unroll
            for (int n = 0; n < 6; ++n) {
                int r = n * 16 + l16;
                int ch = (s * 4 + quad) ^ (r & 7);
                short8 bh = *(const short8*)(bb + r * 128 + ch * 8);
                short8 bl = *(const short8*)(bb + r * 128 + (8 + ch) * 8);
                acc3[n] = __builtin_amdgcn_mfma_f32_16x16x32_bf16(a, bh, acc3[n], 0, 0, 0);
                acc3[n] = __builtin_amdgcn_mfma_f32_16x16x32_bf16(a, bl, acc3[n], 0, 0, 0);
            }
        }
    };
#pragma unroll
    for (int ck = 0; ck <= 2; ++ck) {
        asm volatile("s_waitcnt vmcnt(0)" ::: "memory");
        __builtin_amdgcn_s_barrier();
        __builtin_amdgcn_sched_barrier(0);
        stageB3((ck + 1) & 1, ck + 1);
        compute3(ck);
    }
    asm volatile("s_waitcnt vmcnt(0)" ::: "memory");
    __builtin_amdgcn_s_barrier();
    __builtin_amdgcn_sched_barrier(0);
    compute3(3);

    // epilogue: cols 0-39 -> pH bf16 (ldc=64), 40-79 -> q fp32, 80-95 skip
    int gr0 = bx * 128 + wave * 16 + quad * 4;
#pragma unroll
    for (int n = 0; n < 6; ++n) {
        int gc = n * 16 + l16;
        if (gc >= 80) continue;
#pragma unroll
        for (int r = 0; r < 4; ++r) {
            int gr = gr0 + r;
            if (gr < NN) {
                float v = acc3[n][r];
                if (gc < NCLS) pH[(size_t)gr * 64 + gc] = (short)f2bf(v);
                else           q[(size_t)gr * NCLS + (gc - NCLS)] = v;
            }
        }
    }
}

// ---------------- fused layer-3 aggregation + bias + residual + log_softmax ----------------
__global__ __launch_bounds__(256) void k_final(
    const short* __restrict__ pH, const float* __restrict__ q,
    const int* __restrict__ offs, const int* __restrict__ ssrc,
    const float* __restrict__ bl3, float* __restrict__ out) {
    int wid = (blockIdx.x * 256 + threadIdx.x) >> 6;
    int lane = threadIdx.x & 63;
    if (wid >= NN) return;
    bool act = lane < NCLS;
    int beg = offs[wid], end = offs[wid + 1];
    float a0 = 0.f, a1 = 0.f, a2 = 0.f, a3 = 0.f;
    for (int i = beg; i < end; i += 4) {
        int em1 = end - 1;
        int s0 = ssrc[i];
        int s1 = ssrc[min(i + 1, em1)];
        int s2 = ssrc[min(i + 2, em1)];
        int s3 = ssrc[min(i + 3, em1)];
        float w1 = (i + 1 < end) ? 1.f : 0.f;
        float w2 = (i + 2 < end) ? 1.f : 0.f;
        float w3 = (i + 3 < end) ? 1.f : 0.f;
        if (act) {
            a0 += bf2f((unsigned short)pH[(size_t)s0 * 64 + lane]);
            a1 += w1 * bf2f((unsigned short)pH[(size_t)s1 * 64 + lane]);
            a2 += w2 * bf2f((unsigned short)pH[(size_t)s2 * 64 + lane]);
            a3 += w3 * bf2f((unsigned short)pH[(size_t)s3 * 64 + lane]);
        }
    }
    float inv = 1.f / fmaxf((float)(end - beg), 1.f);
    float v = act ? ((a0 + a1) + (a2 + a3)) * inv + bl3[lane] + q[(size_t)wid * NCLS + lane]
                  : -INFINITY;
    float m = v;
#pragma unroll
    for (int off = 32; off > 0; off >>= 1) m = fmaxf(m, __shfl_xor(m, off));
    float e = act ? expf(v - m) : 0.f;
    float s = e;
#pragma unroll
    for (int off = 32; off > 0; off >>= 1) s += __shfl_xor(s, off);
    float ls = logf(s);
    if (act) out[(size_t)wid * NCLS + lane] = v - m - ls;
}

extern "C" void kernel_launch(void* const* d_in, const int* in_sizes, int n_in,
                              void* d_out, int out_size, void* d_ws, size_t ws_size,
                              hipStream_t stream) {
    const float* x    = (const float*)d_in[0];
    const int*   ei   = (const int*)d_in[1];
    const int*   esrc = ei;        // row 0: src
    const int*   edst = ei + NE;   // row 1: dst
    const float* W_map = (const float*)d_in[2];
    const float* b_map = (const float*)d_in[3];
    const float* Wl1   = (const float*)d_in[4];
    const float* bl1   = (const float*)d_in[5];
    const float* Wr1   = (const float*)d_in[6];
    const float* Wl2   = (const float*)d_in[7];
    const float* bl2   = (const float*)d_in[8];
    const float* Wr2   = (const float*)d_in[9];
    const float* Wl3   = (const float*)d_in[10];
    const float* bl3   = (const float*)d_in[11];
    const float* Wr3   = (const float*)d_in[12];
    float* out = (float*)d_out;

    char* ws = (char*)d_ws;
    short* h0H = (short*)ws; ws += (size_t)NN * 128 * 2;
    short* m0H = (short*)ws; ws += (size_t)NN * 128 * 2;
    short* h1H = (short*)ws; ws += (size_t)NN * 128 * 2;
    short* m1H = (short*)ws; ws += (size_t)NN * 128 * 2;
    short* pH  = (short*)ws; ws += (size_t)NN * 64 * 2;   // bf16, rows padded to 64
    float* q   = (float*)ws; ws += (size_t)NN * NCLS * 4;
    short* wt  = (short*)ws; ws += (size_t)376832 * 2;
    int* deg    = (int*)ws;  ws += (size_t)NN * 4;
    int* offs   = (int*)ws;  ws += (size_t)(NN + 2) * 4;
    int* cursor = (int*)ws;  ws += (size_t)NN * 4;
    int* ssrc   = (int*)ws;  ws += (size_t)NE * 4;
    int* bsum   = (int*)ws;  ws += (size_t)256 * 4;
    int* bpre   = (int*)ws;  ws += (size_t)256 * 4;

    // blocked pre-swizzled weight buffers: [yb][ck64][BN][128], BN=128 (b3w: 96)
    short* m_w  = wt + 0;       // 1yb * 8ck * 128 * 128 = 131072
    short* b1w  = wt + 131072;  // 1yb * 4ck * 128 * 128 = 65536
    short* b2w  = wt + 196608;  // 2yb * 4ck * 128 * 128 = 131072
    short* b3w  = wt + 327680;  // 1yb * 4ck *  96 * 128 = 49152  (total 376832)

    const int g128 = (NN + 127) / 128;  // 391 == G0
    const int aggBlocks = (NN * 64) / 256;
    const int wsb = (WSE + 511) / 512;  // 376

    // --- mega1: degree count + all weight splits (+b3w pad zero) in one dispatch ---
    (void)hipMemsetAsync(deg, 0, (size_t)NN * 4, stream);
    k_mega1<<<CNTB + wsb, 512, 0, stream>>>(edst, deg, W_map, Wr1, Wl1, Wr2, Wl2,
                                            Wl3, Wr3, m_w, b1w, b2w, b3w);

    // --- two-level scan of degrees ---
    k_scan1<<<NB, 256, 0, stream>>>(deg, offs, bsum);
    k_scan2<<<1, 256, 0, stream>>>(bsum, bpre, offs);
    k_scan3<<<NB, 256, 0, stream>>>(offs, bpre, cursor);

    // --- mega2: GEMM0 (h0 = x@W_map + b_map -> h0H) + edge scatter, one dispatch ---
    k_mega2<<<G0 + CNTB, 512, 0, stream>>>(x, m_w, b_map, h0H, esrc, edst, cursor, ssrc);

    // mean(h0) -> m0H
    k_aggb<<<aggBlocks, 256, 0, stream>>>(h0H, offs, ssrc, m0H);

    // h1 = relu([h0|mean] @ [Wr1;Wl1] + bl1) -> h1H
    k_mm8<128, 256, 128, 256, false, true, false><<<dim3(g128, 1), 512, 0, stream>>>(
        (const void*)h0H, m0H, b1w, bl1,
        h1H, 128, nullptr, nullptr, 0, NN, 128);

    // mean(h1) -> m1H
    k_aggb<<<aggBlocks, 256, 0, stream>>>(h1H, offs, ssrc, m1H);

    // fused mm2+mm3: h2 (LDS only) -> pH bf16 + q fp32
    k_mm23<<<g128, 512, 0, stream>>>(h1H, m1H, b2w, bl2, b3w, pH, q);

    // fused: logits = mean_agg(pH) + bl3 + q; log_softmax -> out
    k_final<<<aggBlocks, 256, 0, stream>>>(pH, q, offs, ssrc, bl3, out);
}